// Round 3
// baseline (1908.946 us; speedup 1.0000x reference)
//
#include <hip/hip_runtime.h>
#include <math.h>

typedef unsigned short u16;
typedef unsigned int u32;
typedef __attribute__((ext_vector_type(8))) short short8;
typedef __attribute__((ext_vector_type(4))) float floatx4;

// ---------------- problem constants ----------------
#define BB 64
#define NTOK 197
#define NPATCH 196
#define EMB 192
#define NH 3
#define HD 64
#define FEAT 256
#define MLPD 768
#define NCLS 1000
#define MTOT (BB*NTOK)      // 12608
#define MPAT (BB*NPATCH)    // 12544
#define BHT (BB*NH)         // 192

// ---------------- bf16 helpers ----------------
__device__ __forceinline__ u16 f2bf(float x) {
    u32 u = __builtin_bit_cast(u32, x);
    u32 r = u + 0x7FFFu + ((u >> 16) & 1u);
    return (u16)(r >> 16);
}
__device__ __forceinline__ float bf2f(u16 u) {
    return __builtin_bit_cast(float, (u32)u << 16);
}
__device__ __forceinline__ float sqr8bf(uint4 v) {
    float s = 0.f;
    float t;
    t = bf2f((u16)(v.x & 0xffff)); s += t*t;  t = bf2f((u16)(v.x >> 16)); s += t*t;
    t = bf2f((u16)(v.y & 0xffff)); s += t*t;  t = bf2f((u16)(v.y >> 16)); s += t*t;
    t = bf2f((u16)(v.z & 0xffff)); s += t*t;  t = bf2f((u16)(v.z >> 16)); s += t*t;
    t = bf2f((u16)(v.w & 0xffff)); s += t*t;  t = bf2f((u16)(v.w >> 16)); s += t*t;
    return s;
}

// ---------------- weight prep ----------------
__global__ void cvt_bf16(const float* __restrict__ in, u16* __restrict__ out, int n)
{
    const int i = blockIdx.x * 256 + threadIdx.x;
    if (i < n) out[i] = f2bf(in[i]);
}

// in [L][R][C] fp32 -> out [L][C][R] bf16, coalesced via LDS 32x32 tiles
__global__ void tr_bf16_t(const float* __restrict__ in, u16* __restrict__ out,
                          int R, int C)
{
    __shared__ u16 t[32][33];
    const int l = blockIdx.z;
    const int c0 = blockIdx.x * 32, r0 = blockIdx.y * 32;
    const int tx = threadIdx.x & 31, ty = threadIdx.x >> 5;   // ty 0..7
    const float* ip = in + ((size_t)l * R + r0) * C + c0;
#pragma unroll
    for (int j = 0; j < 4; ++j)
        t[ty + j*8][tx] = f2bf(ip[(size_t)(ty + j*8) * C + tx]);
    __syncthreads();
    u16* op = out + ((size_t)l * C + c0) * R + r0;
#pragma unroll
    for (int j = 0; j < 4; ++j)
        op[(size_t)(ty + j*8) * R + tx] = t[tx][ty + j*8];
}

// ================= persistent-B MFMA GEMM =================
// C[M,N] = A[M,K] @ Bt[N,K]^T + bias. K multiple of 192 (192 or 768).
// Grid (N/64, ceil(M/128)), block 256 (4 waves, each owns a 32-row strip).
// B-slice (64 x 192-k-chunk) staged in LDS once per chunk; A read direct
// from global into MFMA fragments (no A-LDS round trip, 1 barrier/chunk).
// mode 0: fp32 out ; mode 2: gelu -> bf16 ; mode 3: bf16
__global__ __launch_bounds__(256) void gemm_pb(
    const u16* __restrict__ A, const u16* __restrict__ Bt,
    const float* __restrict__ bias,
    float* __restrict__ Cf, u16* __restrict__ Cb,
    int M, int N, int K, int mode)
{
    __shared__ u16 Bs[64][200];
    const int tid = threadIdx.x;
    const int lane = tid & 63, wave = tid >> 6;
    const int l16 = lane & 15, quad = lane >> 4;
    const int n0 = blockIdx.x * 64;
    const int m_strip = blockIdx.y * 128 + wave * 32;

    // B staging coords: 4 threads per row, 48 u16 each
    const int brow = tid >> 2, bkof = (tid & 3) * 48;
    const u16* bp = Bt + (size_t)(n0 + brow) * K + bkof;

    // A row pointers (clamped)
    int r0 = m_strip + l16;        if (r0 > M - 1) r0 = M - 1;
    int r1 = m_strip + 16 + l16;   if (r1 > M - 1) r1 = M - 1;
    const u16* ap0 = A + (size_t)r0 * K + quad * 8;
    const u16* ap1 = A + (size_t)r1 * K + quad * 8;

    floatx4 acc[2][4];
#pragma unroll
    for (int i = 0; i < 2; ++i)
#pragma unroll
        for (int j = 0; j < 4; ++j) acc[i][j] = (floatx4){0.f,0.f,0.f,0.f};

    // preload chunk-0 B regs
    uint4 br[6];
#pragma unroll
    for (int j = 0; j < 6; ++j) br[j] = *(const uint4*)(bp + j * 8);

    const int nch = K / 192;
    for (int c = 0; c < nch; ++c) {
        if (c) __syncthreads();
#pragma unroll
        for (int j = 0; j < 6; ++j) *(uint4*)&Bs[brow][bkof + j * 8] = br[j];
        __syncthreads();

        const int kc = c * 192;
        // A fragments for this chunk (12 x 16B direct loads)
        short8 a[2][6];
#pragma unroll
        for (int ks = 0; ks < 6; ++ks) {
            a[0][ks] = *(const short8*)(ap0 + kc + ks * 32);
            a[1][ks] = *(const short8*)(ap1 + kc + ks * 32);
        }
        // prefetch next chunk's B regs
        if (c + 1 < nch) {
#pragma unroll
            for (int j = 0; j < 6; ++j)
                br[j] = *(const uint4*)(bp + (c + 1) * 192 + j * 8);
        }
#pragma unroll
        for (int ks = 0; ks < 6; ++ks) {
            short8 bf[4];
#pragma unroll
            for (int cf = 0; cf < 4; ++cf)
                bf[cf] = *(const short8*)&Bs[cf * 16 + l16][ks * 32 + quad * 8];
#pragma unroll
            for (int rf = 0; rf < 2; ++rf)
#pragma unroll
                for (int cf = 0; cf < 4; ++cf)
                    acc[rf][cf] = __builtin_amdgcn_mfma_f32_16x16x32_bf16(a[rf][ks], bf[cf], acc[rf][cf], 0, 0, 0);
        }
    }

    const int rbase = m_strip + quad * 4;
    const int cbase = n0 + l16;
#pragma unroll
    for (int rf = 0; rf < 2; ++rf) {
#pragma unroll
        for (int reg = 0; reg < 4; ++reg) {
            const int gm = rbase + rf * 16 + reg;
            if (gm >= M) continue;
#pragma unroll
            for (int cf = 0; cf < 4; ++cf) {
                const int gn = cbase + cf * 16;
                float v = acc[rf][cf][reg] + bias[gn];
                if (mode == 2) {
                    v = 0.5f * v * (1.f + erff(v * 0.70710678118654752f));
                    Cb[(size_t)gm * N + gn] = f2bf(v);
                } else if (mode == 3) {
                    Cb[(size_t)gm * N + gn] = f2bf(v);
                } else {
                    Cf[(size_t)gm * N + gn] = v;
                }
            }
        }
    }
}

// ================= fused GEMM(+bias+residual) + LayerNorm =================
// Tile 64 x 192 (full row), M = 12608 exactly = 197*64.
// A read direct from global (no A-LDS). B staged per 64-k chunk.
__global__ __launch_bounds__(256) void gemm_ln(
    const u16* __restrict__ A, const u16* __restrict__ Bt,
    const float* __restrict__ bias,
    const float* __restrict__ lnw, const float* __restrict__ lnb,
    float* __restrict__ H, u16* __restrict__ outb, int K)
{
    __shared__ u16 Bs[192][72];
    __shared__ float red_s[2][64][2];
    const int tid = threadIdx.x;
    const int lane = tid & 63, wave = tid >> 6;
    const int wr = wave & 1, wc = wave >> 1;
    const int l16 = lane & 15, quad = lane >> 4;
    const int m0 = blockIdx.x * 64;
    const int srow = tid >> 2, skof = (tid & 3) * 16;

    floatx4 acc[2][6];
#pragma unroll
    for (int i = 0; i < 2; ++i)
#pragma unroll
        for (int j = 0; j < 6; ++j) acc[i][j] = (floatx4){0.f,0.f,0.f,0.f};

    const u16* ap0 = A + (size_t)(m0 + wr * 32 + l16) * K + quad * 8;
    const u16* ap1 = A + (size_t)(m0 + wr * 32 + 16 + l16) * K + quad * 8;
    const u16* bp = Bt + (size_t)srow * K + skof;
    const size_t bstep = (size_t)64 * K;

    for (int k0 = 0; k0 < K; k0 += 64) {
        // direct A fragments for this chunk
        short8 a[2][2];
        a[0][0] = *(const short8*)(ap0 + k0);
        a[0][1] = *(const short8*)(ap0 + k0 + 32);
        a[1][0] = *(const short8*)(ap1 + k0);
        a[1][1] = *(const short8*)(ap1 + k0 + 32);
        const uint4 b0 = *(const uint4*)(bp + k0);
        const uint4 b1 = *(const uint4*)(bp + k0 + 8);
        const uint4 b2 = *(const uint4*)(bp + bstep + k0);
        const uint4 b3 = *(const uint4*)(bp + bstep + k0 + 8);
        const uint4 b4 = *(const uint4*)(bp + 2*bstep + k0);
        const uint4 b5 = *(const uint4*)(bp + 2*bstep + k0 + 8);
        if (k0) __syncthreads();
        *(uint4*)&Bs[srow][skof]           = b0;
        *(uint4*)&Bs[srow][skof + 8]       = b1;
        *(uint4*)&Bs[srow + 64][skof]      = b2;
        *(uint4*)&Bs[srow + 64][skof + 8]  = b3;
        *(uint4*)&Bs[srow + 128][skof]     = b4;
        *(uint4*)&Bs[srow + 128][skof + 8] = b5;
        __syncthreads();
#pragma unroll
        for (int ks = 0; ks < 2; ++ks) {
            short8 bf[6];
#pragma unroll
            for (int cf = 0; cf < 6; ++cf)
                bf[cf] = *(const short8*)&Bs[wc*96 + cf*16 + l16][ks*32 + quad*8];
#pragma unroll
            for (int rf = 0; rf < 2; ++rf)
#pragma unroll
                for (int cf = 0; cf < 6; ++cf)
                    acc[rf][cf] = __builtin_amdgcn_mfma_f32_16x16x32_bf16(a[rf][ks], bf[cf], acc[rf][cf], 0, 0, 0);
        }
    }

    // epilogue: bias + residual -> H (fp32), accumulate row sum / sumsq
    float s_[2][4], q_[2][4];
#pragma unroll
    for (int rf = 0; rf < 2; ++rf)
#pragma unroll
        for (int reg = 0; reg < 4; ++reg) { s_[rf][reg] = 0.f; q_[rf][reg] = 0.f; }

#pragma unroll
    for (int rf = 0; rf < 2; ++rf) {
#pragma unroll
        for (int cf = 0; cf < 6; ++cf) {
            const int gn = wc * 96 + cf * 16 + l16;
            const float bia = bias[gn];
#pragma unroll
            for (int reg = 0; reg < 4; ++reg) {
                const int gm = m0 + wr * 32 + rf * 16 + quad * 4 + reg;
                float v = acc[rf][cf][reg] + bia + H[(size_t)gm * EMB + gn];
                H[(size_t)gm * EMB + gn] = v;
                acc[rf][cf][reg] = v;
                s_[rf][reg] += v;
                q_[rf][reg] += v * v;
            }
        }
    }

    if (lnw) {
#pragma unroll
        for (int rf = 0; rf < 2; ++rf)
#pragma unroll
            for (int reg = 0; reg < 4; ++reg) {
                float s = s_[rf][reg], q = q_[rf][reg];
                s += __shfl_xor(s, 1); q += __shfl_xor(q, 1);
                s += __shfl_xor(s, 2); q += __shfl_xor(q, 2);
                s += __shfl_xor(s, 4); q += __shfl_xor(q, 4);
                s += __shfl_xor(s, 8); q += __shfl_xor(q, 8);
                if (l16 == 0) {
                    const int rl = wr * 32 + rf * 16 + quad * 4 + reg;
                    red_s[wc][rl][0] = s;
                    red_s[wc][rl][1] = q;
                }
            }
        __syncthreads();
#pragma unroll
        for (int rf = 0; rf < 2; ++rf) {
#pragma unroll
            for (int reg = 0; reg < 4; ++reg) {
                const int rl = wr * 32 + rf * 16 + quad * 4 + reg;
                const float ts = red_s[0][rl][0] + red_s[1][rl][0];
                const float tq = red_s[0][rl][1] + red_s[1][rl][1];
                const float mu = ts * (1.f / 192.f);
                const float var = tq * (1.f / 192.f) - mu * mu;
                const float rstd = rsqrtf(fmaxf(var, 0.f) + 1e-5f);
                const int gm = m0 + rl;
#pragma unroll
                for (int cf = 0; cf < 6; ++cf) {
                    const int gn = wc * 96 + cf * 16 + l16;
                    const float y = (acc[rf][cf][reg] - mu) * rstd * lnw[gn] + lnb[gn];
                    outb[(size_t)gm * EMB + gn] = f2bf(y);
                }
            }
        }
    }
}

// ================= fused performer attention, stage 1 =====================
__global__ __launch_bounds__(256) void attn_pkv(
    const u16* __restrict__ qkv, const u16* __restrict__ pmb,
    u16* __restrict__ kvT, float* __restrict__ ksum)
{
    __shared__ u16 pm_s[256][72];     // [f][d]
    __shared__ u16 kt_s[64][72];      // [n][d] tile
    __shared__ u16 vT_s[64][72];      // [d][n] tile
    __shared__ u16 pkT_s[256][72];    // [f][n] tile
    __shared__ float nrm_s[64];
    __shared__ float ksum_s[256];

    const int tid = threadIdx.x;
    const int lane = tid & 63, wave = tid >> 6;
    const int l16 = lane & 15, quad = lane >> 4;
    const int bh = blockIdx.x, b = bh / NH, h = bh % NH;
    const int fbase = wave * 64;
    const int srow = tid >> 2, skof = (tid & 3) * 16;
    const float scale = 0.35355339059327373f;

#pragma unroll
    for (int j = 0; j < 8; ++j) {
        const int flat = j * 256 + tid;
        const int f = flat >> 3, o = (flat & 7) * 8;
        *(uint4*)&pm_s[f][o] = *(const uint4*)(pmb + f * 64 + o);
    }
    ksum_s[tid] = 0.f;

    floatx4 kv[4][4];
#pragma unroll
    for (int i = 0; i < 4; ++i)
#pragma unroll
        for (int j = 0; j < 4; ++j) kv[i][j] = (floatx4){0.f,0.f,0.f,0.f};

    uint4 k0v = {0,0,0,0}, k1v = {0,0,0,0}, v0v = {0,0,0,0}, v1v = {0,0,0,0};
    {
        const u16* kp = qkv + ((size_t)(b * NTOK + srow)) * 576 + 192 + h * 64 + skof;
        k0v = *(const uint4*)kp; k1v = *(const uint4*)(kp + 8);
        v0v = *(const uint4*)(kp + 192); v1v = *(const uint4*)(kp + 200);
    }

    for (int t = 0; t < 4; ++t) {
        const int ncur = t * 64 + srow;
        if (t) __syncthreads();
        *(uint4*)&kt_s[srow][skof]     = k0v;
        *(uint4*)&kt_s[srow][skof + 8] = k1v;
        {
            u16 vv[16];
            vv[0]=(u16)(v0v.x&0xffff);  vv[1]=(u16)(v0v.x>>16);
            vv[2]=(u16)(v0v.y&0xffff);  vv[3]=(u16)(v0v.y>>16);
            vv[4]=(u16)(v0v.z&0xffff);  vv[5]=(u16)(v0v.z>>16);
            vv[6]=(u16)(v0v.w&0xffff);  vv[7]=(u16)(v0v.w>>16);
            vv[8]=(u16)(v1v.x&0xffff);  vv[9]=(u16)(v1v.x>>16);
            vv[10]=(u16)(v1v.y&0xffff); vv[11]=(u16)(v1v.y>>16);
            vv[12]=(u16)(v1v.z&0xffff); vv[13]=(u16)(v1v.z>>16);
            vv[14]=(u16)(v1v.w&0xffff); vv[15]=(u16)(v1v.w>>16);
#pragma unroll
            for (int j = 0; j < 16; ++j) vT_s[skof + j][srow] = vv[j];
        }
        float sq = sqr8bf(k0v) + sqr8bf(k1v);
        sq += __shfl_xor(sq, 1);
        sq += __shfl_xor(sq, 2);
        if ((tid & 3) == 0) nrm_s[srow] = (ncur < NTOK) ? 0.5f * sq : 1e30f;
        __syncthreads();

        if (t < 3) {
            const int n = (t + 1) * 64 + srow;
            k0v = (uint4){0,0,0,0}; k1v = (uint4){0,0,0,0};
            v0v = (uint4){0,0,0,0}; v1v = (uint4){0,0,0,0};
            if (n < NTOK) {
                const u16* kp = qkv + ((size_t)(b * NTOK + n)) * 576 + 192 + h * 64 + skof;
                k0v = *(const uint4*)kp; k1v = *(const uint4*)(kp + 8);
                v0v = *(const uint4*)(kp + 192); v1v = *(const uint4*)(kp + 200);
            }
        }

        floatx4 pa[4][4];
#pragma unroll
        for (int i = 0; i < 4; ++i)
#pragma unroll
            for (int j = 0; j < 4; ++j) pa[i][j] = (floatx4){0.f,0.f,0.f,0.f};
#pragma unroll
        for (int ks = 0; ks < 2; ++ks) {
            short8 a[4], bb[4];
#pragma unroll
            for (int rf = 0; rf < 4; ++rf)
                a[rf] = *(const short8*)&kt_s[rf*16 + l16][ks*32 + quad*8];
#pragma unroll
            for (int cf = 0; cf < 4; ++cf)
                bb[cf] = *(const short8*)&pm_s[fbase + cf*16 + l16][ks*32 + quad*8];
#pragma unroll
            for (int rf = 0; rf < 4; ++rf)
#pragma unroll
                for (int cf = 0; cf < 4; ++cf)
                    pa[rf][cf] = __builtin_amdgcn_mfma_f32_16x16x32_bf16(a[rf], bb[cf], pa[rf][cf], 0, 0, 0);
        }

        float ksp[4] = {0.f, 0.f, 0.f, 0.f};
#pragma unroll
        for (int rf = 0; rf < 4; ++rf) {
            const int nl = rf * 16 + quad * 4;
            const float nr0 = nrm_s[nl + 0], nr1 = nrm_s[nl + 1];
            const float nr2 = nrm_s[nl + 2], nr3 = nrm_s[nl + 3];
#pragma unroll
            for (int cf = 0; cf < 4; ++cf) {
                const int f = fbase + cf * 16 + l16;
                const u16 b0 = f2bf(__expf(pa[rf][cf][0] - nr0) * scale);
                const u16 b1 = f2bf(__expf(pa[rf][cf][1] - nr1) * scale);
                const u16 b2 = f2bf(__expf(pa[rf][cf][2] - nr2) * scale);
                const u16 b3 = f2bf(__expf(pa[rf][cf][3] - nr3) * scale);
                ksp[cf] += bf2f(b0) + bf2f(b1) + bf2f(b2) + bf2f(b3);
                *(u32*)&pkT_s[f][nl]     = (u32)b0 | ((u32)b1 << 16);
                *(u32*)&pkT_s[f][nl + 2] = (u32)b2 | ((u32)b3 << 16);
            }
        }
#pragma unroll
        for (int cf = 0; cf < 4; ++cf) {
            float v = ksp[cf];
            v += __shfl_xor(v, 16);
            v += __shfl_xor(v, 32);
            if (quad == 0) ksum_s[fbase + cf*16 + l16] += v;
        }

#pragma unroll
        for (int ks = 0; ks < 2; ++ks) {
            short8 a[4], bb[4];
#pragma unroll
            for (int rf = 0; rf < 4; ++rf)
                a[rf] = *(const short8*)&vT_s[rf*16 + l16][ks*32 + quad*8];
#pragma unroll
            for (int cf = 0; cf < 4; ++cf)
                bb[cf] = *(const short8*)&pkT_s[fbase + cf*16 + l16][ks*32 + quad*8];
#pragma unroll
            for (int rf = 0; rf < 4; ++rf)
#pragma unroll
                for (int cf = 0; cf < 4; ++cf)
                    kv[rf][cf] = __builtin_amdgcn_mfma_f32_16x16x32_bf16(a[rf], bb[cf], kv[rf][cf], 0, 0, 0);
        }
    }

    __syncthreads();
    ksum[(size_t)bh * 256 + tid] = ksum_s[tid];
#pragma unroll
    for (int rf = 0; rf < 4; ++rf)
#pragma unroll
        for (int cf = 0; cf < 4; ++cf) {
            const int f = fbase + cf * 16 + l16;
#pragma unroll
            for (int reg = 0; reg < 4; ++reg) {
                const int d = rf * 16 + quad * 4 + reg;
                kvT[((size_t)bh * 64 + d) * 256 + f] = f2bf(kv[rf][cf][reg]);
            }
        }
}

// ================= fused performer attention, stage 2 =====================
__global__ __launch_bounds__(256) void attn_out(
    const u16* __restrict__ qkv, const u16* __restrict__ pmb,
    const u16* __restrict__ kvT, const float* __restrict__ ksum,
    u16* __restrict__ attn_o)
{
    __shared__ u16 pm_s[256][72];     // [f][d]
    __shared__ u16 q_s[64][72];       // [n][d]
    __shared__ u16 pq_s[64][264];     // [n][f]
    __shared__ u16 kv_s[64][264];     // [d][f]
    __shared__ float nrm_s[64];
    __shared__ float den_s[4][64];

    const int tid = threadIdx.x;
    const int lane = tid & 63, wave = tid >> 6;
    const int l16 = lane & 15, quad = lane >> 4;
    const int bh = blockIdx.y, b = bh / NH, h = bh % NH;
    const int n0 = blockIdx.x * 64;
    const int fbase = wave * 64;
    const int srow = tid >> 2, skof = (tid & 3) * 16;
    const float scale = 0.35355339059327373f;

#pragma unroll
    for (int j = 0; j < 8; ++j) {
        const int flat = j * 256 + tid;
        const int f = flat >> 3, o = (flat & 7) * 8;
        *(uint4*)&pm_s[f][o] = *(const uint4*)(pmb + f * 64 + o);
    }
#pragma unroll
    for (int j = 0; j < 8; ++j) {
        const int flat = j * 256 + tid;
        const int d = flat >> 5, o = (flat & 31) * 8;
        *(uint4*)&kv_s[d][o] = *(const uint4*)(kvT + ((size_t)bh * 64 + d) * 256 + o);
    }
    {
        const int n = n0 + srow;
        uint4 q0 = {0,0,0,0}, q1 = {0,0,0,0};
        if (n < NTOK) {
            const u16* qp = qkv + ((size_t)(b * NTOK + n)) * 576 + h * 64 + skof;
            q0 = *(const uint4*)qp; q1 = *(const uint4*)(qp + 8);
        }
        *(uint4*)&q_s[srow][skof]     = q0;
        *(uint4*)&q_s[srow][skof + 8] = q1;
        float sq = sqr8bf(q0) + sqr8bf(q1);
        sq += __shfl_xor(sq, 1);
        sq += __shfl_xor(sq, 2);
        if ((tid & 3) == 0) nrm_s[srow] = (n < NTOK) ? 0.5f * sq : 1e30f;
    }
    float ksr[4];
#pragma unroll
    for (int cf = 0; cf < 4; ++cf)
        ksr[cf] = ksum[(size_t)bh * 256 + fbase + cf * 16 + l16];
    __syncthreads();

    floatx4 pa[4][4];
#pragma unroll
    for (int i = 0; i < 4; ++i)
#pragma unroll
        for (int j = 0; j < 4; ++j) pa[i][j] = (floatx4){0.f,0.f,0.f,0.f};
#pragma unroll
    for (int ks = 0; ks < 2; ++ks) {
        short8 a[4], bb[4];
#pragma unroll
        for (int rf = 0; rf < 4; ++rf)
            a[rf] = *(const short8*)&q_s[rf*16 + l16][ks*32 + quad*8];
#pragma unroll
        for (int cf = 0; cf < 4; ++cf)
            bb[cf] = *(const short8*)&pm_s[fbase + cf*16 + l16][ks*32 + quad*8];
#pragma unroll
        for (int rf = 0; rf < 4; ++rf)
#pragma unroll
            for (int cf = 0; cf < 4; ++cf)
                pa[rf][cf] = __builtin_amdgcn_mfma_f32_16x16x32_bf16(a[rf], bb[cf], pa[rf][cf], 0, 0, 0);
    }

    float dpart[16];
#pragma unroll
    for (int i = 0; i < 16; ++i) dpart[i] = 0.f;
#pragma unroll
    for (int rf = 0; rf < 4; ++rf) {
        const int nl = rf * 16 + quad * 4;
        const float nr0 = nrm_s[nl + 0], nr1 = nrm_s[nl + 1];
        const float nr2 = nrm_s[nl + 2], nr3 = nrm_s[nl + 3];
#pragma unroll
        for (int cf = 0; cf < 4; ++cf) {
            const int f = fbase + cf * 16 + l16;
            const u16 b0 = f2bf(__expf(pa[rf][cf][0] - nr0) * scale);
            const u16 b1 = f2bf(__expf(pa[rf][cf][1] - nr1) * scale);
            const u16 b2 = f2bf(__expf(pa[rf][cf][2] - nr2) * scale);
            const u16 b3 = f2bf(__expf(pa[rf][cf][3] - nr3) * scale);
            pq_s[nl + 0][f] = b0;
            pq_s[nl + 1][f] = b1;
            pq_s[nl + 2][f] = b2;
            pq_s[nl + 3][f] = b3;
            dpart[rf*4 + 0] += bf2f(b0) * ksr[cf];
            dpart[rf*4 + 1] += bf2f(b1) * ksr[cf];
            dpart[rf*4 + 2] += bf2f(b2) * ksr[cf];
            dpart[rf*4 + 3] += bf2f(b3) * ksr[cf];
        }
    }
#pragma unroll
    for (int i = 0; i < 16; ++i) {
        float d = dpart[i];
        d += __shfl_xor(d, 1); d += __shfl_xor(d, 2);
        d += __shfl_xor(d, 4); d += __shfl_xor(d, 8);
        dpart[i] = d;
    }
    if (l16 == 0) {
#pragma unroll
        for (int rf = 0; rf < 4; ++rf)
#pragma unroll
            for (int reg = 0; reg < 4; ++reg)
                den_s[wave][rf*16 + quad*4 + reg] = dpart[rf*4 + reg];
    }
    __syncthreads();

    const int wr = wave & 1, wc = wave >> 1;
    floatx4 oc[2][2];
#pragma unroll
    for (int i = 0; i < 2; ++i)
#pragma unroll
        for (int j = 0; j < 2; ++j) oc[i][j] = (floatx4){0.f,0.f,0.f,0.f};
#pragma unroll
    for (int ks = 0; ks < 8; ++ks) {
        short8 a[2], bb[2];
#pragma unroll
        for (int rf = 0; rf < 2; ++rf)
            a[rf] = *(const short8*)&pq_s[wr*32 + rf*16 + l16][ks*32 + quad*8];
#pragma unroll
        for (int cf = 0; cf < 2; ++cf)
            bb[cf] = *(const short8*)&kv_s[wc*32 + cf*16 + l16][ks*32 + quad*8];
#pragma unroll
        for (int rf = 0; rf < 2; ++rf)
#pragma unroll
            for (int cf = 0; cf < 2; ++cf)
                oc[rf][cf] = __builtin_amdgcn_mfma_f32_16x16x32_bf16(a[rf], bb[cf], oc[rf][cf], 0, 0, 0);
    }

#pragma unroll
    for (int rf = 0; rf < 2; ++rf) {
#pragma unroll
        for (int reg = 0; reg < 4; ++reg) {
            const int nl = wr*32 + rf*16 + quad*4 + reg;
            const int gn = n0 + nl;
            if (gn >= NTOK) continue;
            const float di = 1.f / (den_s[0][nl] + den_s[1][nl] + den_s[2][nl] + den_s[3][nl]);
#pragma unroll
            for (int cf = 0; cf < 2; ++cf) {
                const int d = wc*32 + cf*16 + l16;
                attn_o[((size_t)(b * NTOK + gn)) * EMB + h * 64 + d] =
                    f2bf(oc[rf][cf][reg] * di);
            }
        }
    }
}

// ---------------- im2col (bf16 out) ----------------
__global__ void im2col_kernel(const float* __restrict__ x, u16* __restrict__ p, int total)
{
    const int i = blockIdx.x * 256 + threadIdx.x;
    if (i >= total) return;
    const int col = i % 768, row = i / 768;
    const int px = col & 15, py = (col >> 4) & 15, c = col >> 8;
    const int gx = row % 14, gy = (row / 14) % 14, b = row / 196;
    p[i] = f2bf(x[((size_t)(b * 3 + c) * 224 + gy * 16 + py) * 224 + gx * 16 + px]);
}

// ---------------- patch-embed finish ----------------
__global__ void embed_finish(const float* __restrict__ tok, const float* __restrict__ cls,
                             const float* __restrict__ pos, const float* __restrict__ w,
                             const float* __restrict__ b, float* __restrict__ h)
{
    const int wid = threadIdx.x >> 6, lane = threadIdx.x & 63;
    const int r = blockIdx.x * 4 + wid;
    if (r >= MTOT) return;
    const int bb = r / NTOK, t = r % NTOK;
    float* q = h + (size_t)r * EMB;
    if (t == 0) {
        q[lane]       = cls[lane]       + pos[lane];
        q[lane + 64]  = cls[lane + 64]  + pos[lane + 64];
        q[lane + 128] = cls[lane + 128] + pos[lane + 128];
        return;
    }
    const float* p = tok + ((size_t)bb * NPATCH + (t - 1)) * EMB;
    float x0 = p[lane], x1 = p[lane + 64], x2 = p[lane + 128];
    float s = x0 + x1 + x2;
#pragma unroll
    for (int off = 32; off; off >>= 1) s += __shfl_xor(s, off);
    const float mu = s * (1.f / 192.f);
    const float d0 = x0 - mu, d1 = x1 - mu, d2 = x2 - mu;
    float v = d0 * d0 + d1 * d1 + d2 * d2;
#pragma unroll
    for (int off = 32; off; off >>= 1) v += __shfl_xor(v, off);
    const float rstd = rsqrtf(v * (1.f / 192.f) + 1e-5f);
    const float* pr = pos + (size_t)t * EMB;
    q[lane]       = d0 * rstd * w[lane]       + b[lane]       + pr[lane];
    q[lane + 64]  = d1 * rstd * w[lane + 64]  + b[lane + 64]  + pr[lane + 64];
    q[lane + 128] = d2 * rstd * w[lane + 128] + b[lane + 128] + pr[lane + 128];
}

// ---------------- LayerNorm over 192; bf16 or fp32 out ----------------
__global__ void ln192(const float* __restrict__ in, int in_stride,
                      const float* __restrict__ w, const float* __restrict__ b,
                      u16* __restrict__ outb, float* __restrict__ outf, int rows)
{
    const int wid = threadIdx.x >> 6, lane = threadIdx.x & 63;
    const int r = blockIdx.x * 4 + wid;
    if (r >= rows) return;
    const float* p = in + (size_t)r * in_stride;
    float x0 = p[lane], x1 = p[lane + 64], x2 = p[lane + 128];
    float s = x0 + x1 + x2;
#pragma unroll
    for (int off = 32; off; off >>= 1) s += __shfl_xor(s, off);
    const float mu = s * (1.f / 192.f);
    const float d0 = x0 - mu, d1 = x1 - mu, d2 = x2 - mu;
    float v = d0 * d0 + d1 * d1 + d2 * d2;
#pragma unroll
    for (int off = 32; off; off >>= 1) v += __shfl_xor(v, off);
    const float rstd = rsqrtf(v * (1.f / 192.f) + 1e-5f);
    const float y0 = d0 * rstd * w[lane]       + b[lane];
    const float y1 = d1 * rstd * w[lane + 64]  + b[lane + 64];
    const float y2 = d2 * rstd * w[lane + 128] + b[lane + 128];
    if (outf) {
        float* q = outf + (size_t)r * EMB;
        q[lane] = y0; q[lane + 64] = y1; q[lane + 128] = y2;
    } else {
        u16* q = outb + (size_t)r * EMB;
        q[lane] = f2bf(y0); q[lane + 64] = f2bf(y1); q[lane + 128] = f2bf(y2);
    }
}

// ---------------- fp32 GEMM (head / exits only) ----------------
__global__ __launch_bounds__(256) void gemm_f32(
    const float* __restrict__ A, const float* __restrict__ Bm,
    const float* __restrict__ bias, float* __restrict__ C,
    int M, int N, int K)
{
    __shared__ float As[16][68];
    __shared__ float Bs[16][64];
    const int tid = threadIdx.x;
    const int tx = tid & 15, ty = tid >> 4;
    const int m0 = blockIdx.y * 64, n0 = blockIdx.x * 64;
    float acc[4][4] = {};

    for (int k0 = 0; k0 < K; k0 += 16) {
        {
            const int c = tid & 15, r4 = tid >> 4;
#pragma unroll
            for (int i = 0; i < 4; ++i) {
                const int r = r4 + i * 16, gm = m0 + r;
                As[c][r] = (gm < M) ? A[(size_t)gm * K + (k0 + c)] : 0.f;
            }
        }
        {
            const int cb = tid & 63, rb4 = tid >> 6;
#pragma unroll
            for (int i = 0; i < 4; ++i) {
                const int rb = rb4 + i * 4;
                const int gn = n0 + cb;
                Bs[rb][cb] = (gn < N) ? Bm[(size_t)(k0 + rb) * N + gn] : 0.f;
            }
        }
        __syncthreads();
#pragma unroll
        for (int kk = 0; kk < 16; ++kk) {
            const float4 av = *reinterpret_cast<const float4*>(&As[kk][ty * 4]);
            const float4 bv = *reinterpret_cast<const float4*>(&Bs[kk][tx * 4]);
            const float a_[4] = {av.x, av.y, av.z, av.w};
            const float b_[4] = {bv.x, bv.y, bv.z, bv.w};
#pragma unroll
            for (int i2 = 0; i2 < 4; ++i2)
#pragma unroll
                for (int j2 = 0; j2 < 4; ++j2)
                    acc[i2][j2] = fmaf(a_[i2], b_[j2], acc[i2][j2]);
        }
        __syncthreads();
    }

#pragma unroll
    for (int i = 0; i < 4; ++i) {
        const int gm = m0 + ty * 4 + i;
        if (gm >= M) continue;
#pragma unroll
        for (int j = 0; j < 4; ++j) {
            const int gn = n0 + tx * 4 + j;
            if (gn >= N) continue;
            C[(size_t)gm * N + gn] = acc[i][j] + bias[gn];
        }
    }
}

// ---------------- mean over tokens for exits (coalesced) ----------------
__global__ void pool_kernel(const float* __restrict__ h, float* __restrict__ pooled)
{
    __shared__ float red[192];
    const int b = blockIdx.x;
    const int slice = threadIdx.x / 192;       // 0..1  (384 threads)
    const int e = threadIdx.x % 192;
    float s = 0.f;
    for (int n = slice; n < NTOK; n += 2)
        s += h[((size_t)(b * NTOK + n)) * EMB + e];
    if (slice == 1) red[e] = s;
    __syncthreads();
    if (slice == 0)
        pooled[b * EMB + e] = (s + red[e]) * (1.f / 197.f);
}

// ---------------- host launch ----------------
extern "C" void kernel_launch(void* const* d_in, const int* in_sizes, int n_in,
                              void* d_out, int out_size, void* d_ws, size_t ws_size,
                              hipStream_t stream)
{
    const float* x          = (const float*)d_in[0];
    const float* patch_w    = (const float*)d_in[1];
    const float* patch_b    = (const float*)d_in[2];
    const float* pe_norm_w  = (const float*)d_in[3];
    const float* pe_norm_b  = (const float*)d_in[4];
    const float* cls_token  = (const float*)d_in[5];
    const float* pos_embed  = (const float*)d_in[6];
    const float* norm1_w    = (const float*)d_in[7];
    const float* norm1_b    = (const float*)d_in[8];
    const float* qkv_w      = (const float*)d_in[9];
    const float* qkv_b      = (const float*)d_in[10];
    const float* proj_mat   = (const float*)d_in[11];
    const float* attn_pw    = (const float*)d_in[12];
    const float* attn_pb    = (const float*)d_in[13];
    const float* norm2_w    = (const float*)d_in[14];
    const float* norm2_b    = (const float*)d_in[15];
    const float* fc1_w      = (const float*)d_in[16];
    const float* fc1_b      = (const float*)d_in[17];
    const float* fc2_w      = (const float*)d_in[18];
    const float* fc2_b      = (const float*)d_in[19];
    const float* exit_w     = (const float*)d_in[20];
    const float* exit_b     = (const float*)d_in[21];
    const float* fnorm_w    = (const float*)d_in[22];
    const float* fnorm_b    = (const float*)d_in[23];
    const float* head_w     = (const float*)d_in[24];
    const float* head_b     = (const float*)d_in[25];
    float* out = (float*)d_out;

    float* ws = (float*)d_ws;
    float* H     = ws + 0;                  // 12608*192 fp32
    u16*   QKVB  = (u16*)(ws + 2420736);    // 12608*576 bf16
    u16*   XLNB  = (u16*)(ws + 6051840);    // 12608*192 bf16
    u16*   KVT   = (u16*)(ws + 19968000);   // 192*64*256 bf16
    u16*   MIDB  = (u16*)(ws + 21540864);   // 12608*768 bf16
    u16*   ATNB  = (u16*)(ws + 26382336);   // 12608*192 bf16
    float* XLNF  = ws + 27592704;           // 64*192
    float* POOL  = ws + 27604992;           // 64*192
    float* KSUM  = ws + 27617280;           // 192*256
    u16*   QKVWT = (u16*)(ws + 27666432);   // 12*576*192 bf16
    u16*   APWT  = (u16*)(ws + 28329984);   // 12*192*192 bf16
    u16*   F1WT  = (u16*)(ws + 28551168);   // 12*768*192 bf16
    u16*   F2WT  = (u16*)(ws + 29435904);   // 12*192*768 bf16
    u16*   PATWB = (u16*)(ws + 30320640);   // 192*768 bf16
    u16*   PMB   = (u16*)(ws + 30394368);   // 12*256*64 bf16
    u16*   P_IMB = MIDB;                    // im2col alias (prologue only)
    float* TOK   = (float*)QKVB;            // patch tokens alias (prologue only)

    if (ws_size < (size_t)30492672 * sizeof(float)) return;

    // ---- weight prep ----
    cvt_bf16<<<(147456 + 255) / 256, 256, 0, stream>>>(patch_w, PATWB, 147456);
    cvt_bf16<<<(196608 + 255) / 256, 256, 0, stream>>>(proj_mat, PMB, 196608);
    tr_bf16_t<<<dim3(18, 6, 12), 256, 0, stream>>>(qkv_w,   QKVWT, 192, 576);
    tr_bf16_t<<<dim3(6, 6, 12),  256, 0, stream>>>(attn_pw, APWT,  192, 192);
    tr_bf16_t<<<dim3(24, 6, 12), 256, 0, stream>>>(fc1_w,   F1WT,  192, 768);
    tr_bf16_t<<<dim3(6, 24, 12), 256, 0, stream>>>(fc2_w,   F2WT,  768, 192);

    // ---- patch embed ----
    im2col_kernel<<<(MPAT * 768 + 255) / 256, 256, 0, stream>>>(x, P_IMB, MPAT * 768);
    gemm_pb<<<dim3(3, 98), 256, 0, stream>>>(P_IMB, PATWB, patch_b,
                                             TOK, nullptr, MPAT, EMB, 768, 0);
    embed_finish<<<(MTOT + 3) / 4, 256, 0, stream>>>(TOK, cls_token, pos_embed,
                                                     pe_norm_w, pe_norm_b, H);
    ln192<<<(MTOT + 3) / 4, 256, 0, stream>>>(H, EMB, norm1_w, norm1_b,
                                              XLNB, nullptr, MTOT);

    // ---- transformer layers ----
    for (int i = 0; i < 12; ++i) {
        const u16* qwt  = QKVWT + (size_t)i * 576 * 192;
        const u16* pwt  = APWT  + (size_t)i * 192 * 192;
        const u16* f1wt = F1WT  + (size_t)i * 768 * 192;
        const u16* f2wt = F2WT  + (size_t)i * 192 * 768;
        const u16* pmb  = PMB   + (size_t)i * 256 * 64;
        const float* qb  = qkv_b   + (size_t)i * 576;
        const float* pb  = attn_pb + (size_t)i * 192;
        const float* f1b = fc1_b   + (size_t)i * 768;
        const float* f2b = fc2_b   + (size_t)i * 192;

        gemm_pb<<<dim3(9, 99), 256, 0, stream>>>(XLNB, qwt, qb,
                                                 nullptr, QKVB, MTOT, 576, 192, 3);
        attn_pkv<<<dim3(BHT), 256, 0, stream>>>(QKVB, pmb, KVT, KSUM);
        attn_out<<<dim3(4, BHT), 256, 0, stream>>>(QKVB, pmb, KVT, KSUM, ATNB);
        gemm_ln<<<197, 256, 0, stream>>>(ATNB, pwt, pb,
                                         norm2_w + (size_t)i * EMB, norm2_b + (size_t)i * EMB,
                                         H, XLNB, EMB);
        gemm_pb<<<dim3(12, 99), 256, 0, stream>>>(XLNB, f1wt, f1b,
                                                  nullptr, MIDB, MTOT, MLPD, 192, 2);
        const float* nw = (i < 11) ? norm1_w + (size_t)(i + 1) * EMB : nullptr;
        const float* nb = (i < 11) ? norm1_b + (size_t)(i + 1) * EMB : nullptr;
        gemm_ln<<<197, 256, 0, stream>>>(MIDB, f2wt, f2b, nw, nb, H, XLNB, MLPD);

        const int e = (i == 3) ? 0 : (i == 7) ? 1 : (i == 11) ? 2 : -1;
        if (e >= 0) {
            pool_kernel<<<BB, 384, 0, stream>>>(H, POOL);
            gemm_f32<<<dim3(16, 1), 256, 0, stream>>>(POOL, exit_w + (size_t)e * 192 * 1000,
                                                      exit_b + (size_t)e * 1000,
                                                      out + (size_t)(1 + e) * BB * NCLS,
                                                      BB, NCLS, EMB);
        }
    }

    // ---- head ----
    ln192<<<(BB + 3) / 4, 256, 0, stream>>>(H, NTOK * EMB, fnorm_w, fnorm_b,
                                            nullptr, XLNF, BB);
    gemm_f32<<<dim3(16, 1), 256, 0, stream>>>(XLNF, head_w, head_b, out, BB, NCLS, EMB);
}

// Round 4
// 1540.234 us; speedup vs baseline: 1.2394x; 1.2394x over previous
//
#include <hip/hip_runtime.h>
#include <math.h>

typedef unsigned short u16;
typedef unsigned int u32;
typedef __attribute__((ext_vector_type(8))) short short8;
typedef __attribute__((ext_vector_type(4))) float floatx4;

// ---------------- problem constants ----------------
#define BB 64
#define NTOK 197
#define NPATCH 196
#define EMB 192
#define NH 3
#define HD 64
#define FEAT 256
#define MLPD 768
#define NCLS 1000
#define MTOT (BB*NTOK)      // 12608
#define MPAT (BB*NPATCH)    // 12544
#define BHT (BB*NH)         // 192

// ---------------- bf16 helpers ----------------
__device__ __forceinline__ u16 f2bf(float x) {
    u32 u = __builtin_bit_cast(u32, x);
    u32 r = u + 0x7FFFu + ((u >> 16) & 1u);
    return (u16)(r >> 16);
}
__device__ __forceinline__ float bf2f(u16 u) {
    return __builtin_bit_cast(float, (u32)u << 16);
}
__device__ __forceinline__ float sqr8bf(uint4 v) {
    float s = 0.f;
    float t;
    t = bf2f((u16)(v.x & 0xffff)); s += t*t;  t = bf2f((u16)(v.x >> 16)); s += t*t;
    t = bf2f((u16)(v.y & 0xffff)); s += t*t;  t = bf2f((u16)(v.y >> 16)); s += t*t;
    t = bf2f((u16)(v.z & 0xffff)); s += t*t;  t = bf2f((u16)(v.z >> 16)); s += t*t;
    t = bf2f((u16)(v.w & 0xffff)); s += t*t;  t = bf2f((u16)(v.w >> 16)); s += t*t;
    return s;
}

// ---------------- weight prep ----------------
__global__ void cvt_bf16(const float* __restrict__ in, u16* __restrict__ out, int n)
{
    const int i = blockIdx.x * 256 + threadIdx.x;
    if (i < n) out[i] = f2bf(in[i]);
}

// in [L][R][C] fp32 -> out [L][C][R] bf16, coalesced via LDS 32x32 tiles
__global__ void tr_bf16_t(const float* __restrict__ in, u16* __restrict__ out,
                          int R, int C)
{
    __shared__ u16 t[32][33];
    const int l = blockIdx.z;
    const int c0 = blockIdx.x * 32, r0 = blockIdx.y * 32;
    const int tx = threadIdx.x & 31, ty = threadIdx.x >> 5;   // ty 0..7
    const float* ip = in + ((size_t)l * R + r0) * C + c0;
#pragma unroll
    for (int j = 0; j < 4; ++j)
        t[ty + j*8][tx] = f2bf(ip[(size_t)(ty + j*8) * C + tx]);
    __syncthreads();
    u16* op = out + ((size_t)l * C + c0) * R + r0;
#pragma unroll
    for (int j = 0; j < 4; ++j)
        op[(size_t)(ty + j*8) * R + tx] = t[tx][ty + j*8];
}

// ================= MFMA bf16 GEMM, 128x64 tile, XCD-swizzled =================
// C[M,N] = A[M,K] @ Bt[N,K]^T + bias.  Grid = 1D (mtiles*ntx) with bijective
// XCD-chunked swizzle (each XCD owns a contiguous m-range -> A-strip L2 reuse).
// mode 0: fp32 out (direct, full-line stores) ; mode 2: gelu->bf16 ; mode 3: bf16
// bf16 modes store via swizzled LDS tile -> coalesced uint4 global stores.
__global__ __launch_bounds__(256) void gemm_bf16(
    const u16* __restrict__ A, const u16* __restrict__ Bt,
    const float* __restrict__ bias,
    float* __restrict__ Cf, u16* __restrict__ Cb,
    int M, int N, int K, int mode, int ntx)
{
    __shared__ u16 As[128][72];
    __shared__ u16 Bs[64][72];
    const int tid = threadIdx.x;
    const int lane = tid & 63, wave = tid >> 6;
    const int l16 = lane & 15, quad = lane >> 4;
    // bijective XCD-chunked swizzle (m204): xcd = bid%8 owns contiguous wg range
    const int nwg = gridDim.x;
    const int q = nwg >> 3, r = nwg & 7;
    const int xcd = blockIdx.x & 7, jj = blockIdx.x >> 3;
    const int wg = (xcd < r ? xcd * (q + 1) : r * (q + 1) + (xcd - r) * q) + jj;
    const int m0 = (wg / ntx) * 128, n0 = (wg % ntx) * 64;
    const int arow = tid >> 1, aof = (tid & 1) * 32;   // 32 u16 per thread
    const int brow = tid >> 2, bof = (tid & 3) * 16;   // 16 u16 per thread

    floatx4 acc[2][4];
#pragma unroll
    for (int i = 0; i < 2; ++i)
#pragma unroll
        for (int j = 0; j < 4; ++j) acc[i][j] = (floatx4){0.f,0.f,0.f,0.f};

    const int gmA = m0 + arow;
    const bool aok = (gmA < M);
    const u16* ap = A + (size_t)gmA * K + aof;
    const u16* bp = Bt + (size_t)(n0 + brow) * K + bof;

    for (int k0 = 0; k0 < K; k0 += 64) {
        uint4 a0 = {0,0,0,0}, a1 = {0,0,0,0}, a2 = {0,0,0,0}, a3 = {0,0,0,0};
        if (aok) {
            a0 = *(const uint4*)(ap + k0);
            a1 = *(const uint4*)(ap + k0 + 8);
            a2 = *(const uint4*)(ap + k0 + 16);
            a3 = *(const uint4*)(ap + k0 + 24);
        }
        const uint4 b0 = *(const uint4*)(bp + k0);
        const uint4 b1 = *(const uint4*)(bp + k0 + 8);
        if (k0) __syncthreads();
        *(uint4*)&As[arow][aof]      = a0;
        *(uint4*)&As[arow][aof + 8]  = a1;
        *(uint4*)&As[arow][aof + 16] = a2;
        *(uint4*)&As[arow][aof + 24] = a3;
        *(uint4*)&Bs[brow][bof]      = b0;
        *(uint4*)&Bs[brow][bof + 8]  = b1;
        __syncthreads();
#pragma unroll
        for (int ks = 0; ks < 2; ++ks) {
            short8 af[2], bf[4];
#pragma unroll
            for (int rf = 0; rf < 2; ++rf)
                af[rf] = *(const short8*)&As[wave*32 + rf*16 + l16][ks*32 + quad*8];
#pragma unroll
            for (int cf = 0; cf < 4; ++cf)
                bf[cf] = *(const short8*)&Bs[cf*16 + l16][ks*32 + quad*8];
#pragma unroll
            for (int rf = 0; rf < 2; ++rf)
#pragma unroll
                for (int cf = 0; cf < 4; ++cf)
                    acc[rf][cf] = __builtin_amdgcn_mfma_f32_16x16x32_bf16(af[rf], bf[cf], acc[rf][cf], 0, 0, 0);
        }
    }

    if (mode == 0) {
        const int rbase = m0 + wave * 32 + quad * 4;
        const int cbase = n0 + l16;
#pragma unroll
        for (int rf = 0; rf < 2; ++rf) {
#pragma unroll
            for (int reg = 0; reg < 4; ++reg) {
                const int gm = rbase + rf * 16 + reg;
                if (gm >= M) continue;
#pragma unroll
                for (int cf = 0; cf < 4; ++cf) {
                    const int gn = cbase + cf * 16;
                    Cf[(size_t)gm * N + gn] = acc[rf][cf][reg] + bias[gn];
                }
            }
        }
        return;
    }

    // bf16 epilogue: bias(+gelu) -> swizzled LDS tile -> coalesced uint4 stores
    __syncthreads();   // all waves done reading As/Bs
#pragma unroll
    for (int rf = 0; rf < 2; ++rf) {
#pragma unroll
        for (int cf = 0; cf < 4; ++cf) {
            const int lc = cf * 16 + l16;
            const float bia = bias[n0 + lc];
#pragma unroll
            for (int reg = 0; reg < 4; ++reg) {
                const int lr = wave * 32 + rf * 16 + quad * 4 + reg;
                float v = acc[rf][cf][reg] + bia;
                if (mode == 2)
                    v = 0.5f * v * (1.f + erff(v * 0.70710678118654752f));
                const int phys = (((lc >> 3) ^ (lr & 7)) << 3) | (lc & 7);
                As[lr][phys] = f2bf(v);
            }
        }
    }
    __syncthreads();
#pragma unroll
    for (int it = 0; it < 4; ++it) {
        const int idx = it * 256 + tid;
        const int row = idx >> 3, c8 = idx & 7;
        const int pc8 = c8 ^ (row & 7);
        const uint4 val = *(const uint4*)&As[row][pc8 * 8];
        const int gm = m0 + row;
        if (gm < M)
            *(uint4*)&Cb[(size_t)gm * N + n0 + c8 * 8] = val;
    }
}

// ================= fused GEMM(+bias+residual) + LayerNorm =================
// Tile 64 x 192 (full row), M = 12608 exactly = 197*64.
__global__ __launch_bounds__(256) void gemm_ln(
    const u16* __restrict__ A, const u16* __restrict__ Bt,
    const float* __restrict__ bias,
    const float* __restrict__ lnw, const float* __restrict__ lnb,
    float* __restrict__ H, u16* __restrict__ outb, int K)
{
    __shared__ u16 As[64][72];
    __shared__ u16 Bs[192][72];
    __shared__ float red_s[2][64][2];
    const int tid = threadIdx.x;
    const int lane = tid & 63, wave = tid >> 6;
    const int wr = wave & 1, wc = wave >> 1;
    const int l16 = lane & 15, quad = lane >> 4;
    const int m0 = blockIdx.x * 64;
    const int srow = tid >> 2, skof = (tid & 3) * 16;

    floatx4 acc[2][6];
#pragma unroll
    for (int i = 0; i < 2; ++i)
#pragma unroll
        for (int j = 0; j < 6; ++j) acc[i][j] = (floatx4){0.f,0.f,0.f,0.f};

    const u16* ap = A + (size_t)(m0 + srow) * K + skof;
    const u16* bp = Bt + (size_t)srow * K + skof;
    const size_t bstep = (size_t)64 * K;

    for (int k0 = 0; k0 < K; k0 += 64) {
        const uint4 a0 = *(const uint4*)(ap + k0);
        const uint4 a1 = *(const uint4*)(ap + k0 + 8);
        const uint4 b0 = *(const uint4*)(bp + k0);
        const uint4 b1 = *(const uint4*)(bp + k0 + 8);
        const uint4 b2 = *(const uint4*)(bp + bstep + k0);
        const uint4 b3 = *(const uint4*)(bp + bstep + k0 + 8);
        const uint4 b4 = *(const uint4*)(bp + 2*bstep + k0);
        const uint4 b5 = *(const uint4*)(bp + 2*bstep + k0 + 8);
        if (k0) __syncthreads();
        *(uint4*)&As[srow][skof]           = a0;
        *(uint4*)&As[srow][skof + 8]       = a1;
        *(uint4*)&Bs[srow][skof]           = b0;
        *(uint4*)&Bs[srow][skof + 8]       = b1;
        *(uint4*)&Bs[srow + 64][skof]      = b2;
        *(uint4*)&Bs[srow + 64][skof + 8]  = b3;
        *(uint4*)&Bs[srow + 128][skof]     = b4;
        *(uint4*)&Bs[srow + 128][skof + 8] = b5;
        __syncthreads();
#pragma unroll
        for (int ks = 0; ks < 2; ++ks) {
            short8 af[2], bf[6];
#pragma unroll
            for (int rf = 0; rf < 2; ++rf)
                af[rf] = *(const short8*)&As[wr*32 + rf*16 + l16][ks*32 + quad*8];
#pragma unroll
            for (int cf = 0; cf < 6; ++cf)
                bf[cf] = *(const short8*)&Bs[wc*96 + cf*16 + l16][ks*32 + quad*8];
#pragma unroll
            for (int rf = 0; rf < 2; ++rf)
#pragma unroll
                for (int cf = 0; cf < 6; ++cf)
                    acc[rf][cf] = __builtin_amdgcn_mfma_f32_16x16x32_bf16(af[rf], bf[cf], acc[rf][cf], 0, 0, 0);
        }
    }

    // epilogue: bias + residual -> H (fp32), accumulate row sum / sumsq
    float s_[2][4], q_[2][4];
#pragma unroll
    for (int rf = 0; rf < 2; ++rf)
#pragma unroll
        for (int reg = 0; reg < 4; ++reg) { s_[rf][reg] = 0.f; q_[rf][reg] = 0.f; }

#pragma unroll
    for (int rf = 0; rf < 2; ++rf) {
#pragma unroll
        for (int cf = 0; cf < 6; ++cf) {
            const int gn = wc * 96 + cf * 16 + l16;
            const float bia = bias[gn];
#pragma unroll
            for (int reg = 0; reg < 4; ++reg) {
                const int gm = m0 + wr * 32 + rf * 16 + quad * 4 + reg;
                float v = acc[rf][cf][reg] + bia + H[(size_t)gm * EMB + gn];
                H[(size_t)gm * EMB + gn] = v;
                acc[rf][cf][reg] = v;
                s_[rf][reg] += v;
                q_[rf][reg] += v * v;
            }
        }
    }

    if (lnw) {
#pragma unroll
        for (int rf = 0; rf < 2; ++rf)
#pragma unroll
            for (int reg = 0; reg < 4; ++reg) {
                float s = s_[rf][reg], q = q_[rf][reg];
                s += __shfl_xor(s, 1); q += __shfl_xor(q, 1);
                s += __shfl_xor(s, 2); q += __shfl_xor(q, 2);
                s += __shfl_xor(s, 4); q += __shfl_xor(q, 4);
                s += __shfl_xor(s, 8); q += __shfl_xor(q, 8);
                if (l16 == 0) {
                    const int rl = wr * 32 + rf * 16 + quad * 4 + reg;
                    red_s[wc][rl][0] = s;
                    red_s[wc][rl][1] = q;
                }
            }
        __syncthreads();
#pragma unroll
        for (int rf = 0; rf < 2; ++rf) {
#pragma unroll
            for (int reg = 0; reg < 4; ++reg) {
                const int rl = wr * 32 + rf * 16 + quad * 4 + reg;
                const float ts = red_s[0][rl][0] + red_s[1][rl][0];
                const float tq = red_s[0][rl][1] + red_s[1][rl][1];
                const float mu = ts * (1.f / 192.f);
                const float var = tq * (1.f / 192.f) - mu * mu;
                const float rstd = rsqrtf(fmaxf(var, 0.f) + 1e-5f);
                const int gm = m0 + rl;
#pragma unroll
                for (int cf = 0; cf < 6; ++cf) {
                    const int gn = wc * 96 + cf * 16 + l16;
                    const float y = (acc[rf][cf][reg] - mu) * rstd * lnw[gn] + lnb[gn];
                    outb[(size_t)gm * EMB + gn] = f2bf(y);
                }
            }
        }
    }
}

// ================= fused performer attention, stage 1 =====================
__global__ __launch_bounds__(256) void attn_pkv(
    const u16* __restrict__ qkv, const u16* __restrict__ pmb,
    u16* __restrict__ kvT, float* __restrict__ ksum)
{
    __shared__ u16 pm_s[256][72];     // [f][d]
    __shared__ u16 kt_s[64][72];      // [n][d] tile
    __shared__ u16 vT_s[64][72];      // [d][n] tile
    __shared__ u16 pkT_s[256][72];    // [f][n] tile
    __shared__ float nrm_s[64];
    __shared__ float ksum_s[256];

    const int tid = threadIdx.x;
    const int lane = tid & 63, wave = tid >> 6;
    const int l16 = lane & 15, quad = lane >> 4;
    const int bh = blockIdx.x, b = bh / NH, h = bh % NH;
    const int fbase = wave * 64;
    const int srow = tid >> 2, skof = (tid & 3) * 16;
    const float scale = 0.35355339059327373f;

#pragma unroll
    for (int j = 0; j < 8; ++j) {
        const int flat = j * 256 + tid;
        const int f = flat >> 3, o = (flat & 7) * 8;
        *(uint4*)&pm_s[f][o] = *(const uint4*)(pmb + f * 64 + o);
    }
    ksum_s[tid] = 0.f;

    floatx4 kv[4][4];
#pragma unroll
    for (int i = 0; i < 4; ++i)
#pragma unroll
        for (int j = 0; j < 4; ++j) kv[i][j] = (floatx4){0.f,0.f,0.f,0.f};

    uint4 k0v = {0,0,0,0}, k1v = {0,0,0,0}, v0v = {0,0,0,0}, v1v = {0,0,0,0};
    {
        const u16* kp = qkv + ((size_t)(b * NTOK + srow)) * 576 + 192 + h * 64 + skof;
        k0v = *(const uint4*)kp; k1v = *(const uint4*)(kp + 8);
        v0v = *(const uint4*)(kp + 192); v1v = *(const uint4*)(kp + 200);
    }

    for (int t = 0; t < 4; ++t) {
        const int ncur = t * 64 + srow;
        if (t) __syncthreads();
        *(uint4*)&kt_s[srow][skof]     = k0v;
        *(uint4*)&kt_s[srow][skof + 8] = k1v;
        {
            u16 vv[16];
            vv[0]=(u16)(v0v.x&0xffff);  vv[1]=(u16)(v0v.x>>16);
            vv[2]=(u16)(v0v.y&0xffff);  vv[3]=(u16)(v0v.y>>16);
            vv[4]=(u16)(v0v.z&0xffff);  vv[5]=(u16)(v0v.z>>16);
            vv[6]=(u16)(v0v.w&0xffff);  vv[7]=(u16)(v0v.w>>16);
            vv[8]=(u16)(v1v.x&0xffff);  vv[9]=(u16)(v1v.x>>16);
            vv[10]=(u16)(v1v.y&0xffff); vv[11]=(u16)(v1v.y>>16);
            vv[12]=(u16)(v1v.z&0xffff); vv[13]=(u16)(v1v.z>>16);
            vv[14]=(u16)(v1v.w&0xffff); vv[15]=(u16)(v1v.w>>16);
#pragma unroll
            for (int j = 0; j < 16; ++j) vT_s[skof + j][srow] = vv[j];
        }
        float sq = sqr8bf(k0v) + sqr8bf(k1v);
        sq += __shfl_xor(sq, 1);
        sq += __shfl_xor(sq, 2);
        if ((tid & 3) == 0) nrm_s[srow] = (ncur < NTOK) ? 0.5f * sq : 1e30f;
        __syncthreads();

        if (t < 3) {
            const int n = (t + 1) * 64 + srow;
            k0v = (uint4){0,0,0,0}; k1v = (uint4){0,0,0,0};
            v0v = (uint4){0,0,0,0}; v1v = (uint4){0,0,0,0};
            if (n < NTOK) {
                const u16* kp = qkv + ((size_t)(b * NTOK + n)) * 576 + 192 + h * 64 + skof;
                k0v = *(const uint4*)kp; k1v = *(const uint4*)(kp + 8);
                v0v = *(const uint4*)(kp + 192); v1v = *(const uint4*)(kp + 200);
            }
        }

        floatx4 pa[4][4];
#pragma unroll
        for (int i = 0; i < 4; ++i)
#pragma unroll
            for (int j = 0; j < 4; ++j) pa[i][j] = (floatx4){0.f,0.f,0.f,0.f};
#pragma unroll
        for (int ks = 0; ks < 2; ++ks) {
            short8 a[4], bb[4];
#pragma unroll
            for (int rf = 0; rf < 4; ++rf)
                a[rf] = *(const short8*)&kt_s[rf*16 + l16][ks*32 + quad*8];
#pragma unroll
            for (int cf = 0; cf < 4; ++cf)
                bb[cf] = *(const short8*)&pm_s[fbase + cf*16 + l16][ks*32 + quad*8];
#pragma unroll
            for (int rf = 0; rf < 4; ++rf)
#pragma unroll
                for (int cf = 0; cf < 4; ++cf)
                    pa[rf][cf] = __builtin_amdgcn_mfma_f32_16x16x32_bf16(a[rf], bb[cf], pa[rf][cf], 0, 0, 0);
        }

        float ksp[4] = {0.f, 0.f, 0.f, 0.f};
#pragma unroll
        for (int rf = 0; rf < 4; ++rf) {
            const int nl = rf * 16 + quad * 4;
            const float nr0 = nrm_s[nl + 0], nr1 = nrm_s[nl + 1];
            const float nr2 = nrm_s[nl + 2], nr3 = nrm_s[nl + 3];
#pragma unroll
            for (int cf = 0; cf < 4; ++cf) {
                const int f = fbase + cf * 16 + l16;
                const u16 b0 = f2bf(__expf(pa[rf][cf][0] - nr0) * scale);
                const u16 b1 = f2bf(__expf(pa[rf][cf][1] - nr1) * scale);
                const u16 b2 = f2bf(__expf(pa[rf][cf][2] - nr2) * scale);
                const u16 b3 = f2bf(__expf(pa[rf][cf][3] - nr3) * scale);
                ksp[cf] += bf2f(b0) + bf2f(b1) + bf2f(b2) + bf2f(b3);
                *(u32*)&pkT_s[f][nl]     = (u32)b0 | ((u32)b1 << 16);
                *(u32*)&pkT_s[f][nl + 2] = (u32)b2 | ((u32)b3 << 16);
            }
        }
#pragma unroll
        for (int cf = 0; cf < 4; ++cf) {
            float v = ksp[cf];
            v += __shfl_xor(v, 16);
            v += __shfl_xor(v, 32);
            if (quad == 0) ksum_s[fbase + cf*16 + l16] += v;
        }

#pragma unroll
        for (int ks = 0; ks < 2; ++ks) {
            short8 a[4], bb[4];
#pragma unroll
            for (int rf = 0; rf < 4; ++rf)
                a[rf] = *(const short8*)&vT_s[rf*16 + l16][ks*32 + quad*8];
#pragma unroll
            for (int cf = 0; cf < 4; ++cf)
                bb[cf] = *(const short8*)&pkT_s[fbase + cf*16 + l16][ks*32 + quad*8];
#pragma unroll
            for (int rf = 0; rf < 4; ++rf)
#pragma unroll
                for (int cf = 0; cf < 4; ++cf)
                    kv[rf][cf] = __builtin_amdgcn_mfma_f32_16x16x32_bf16(a[rf], bb[cf], kv[rf][cf], 0, 0, 0);
        }
    }

    __syncthreads();
    ksum[(size_t)bh * 256 + tid] = ksum_s[tid];
#pragma unroll
    for (int rf = 0; rf < 4; ++rf)
#pragma unroll
        for (int cf = 0; cf < 4; ++cf) {
            const int f = fbase + cf * 16 + l16;
#pragma unroll
            for (int reg = 0; reg < 4; ++reg) {
                const int d = rf * 16 + quad * 4 + reg;
                kvT[((size_t)bh * 64 + d) * 256 + f] = f2bf(kv[rf][cf][reg]);
            }
        }
}

// ================= fused performer attention, stage 2 =====================
__global__ __launch_bounds__(256) void attn_out(
    const u16* __restrict__ qkv, const u16* __restrict__ pmb,
    const u16* __restrict__ kvT, const float* __restrict__ ksum,
    u16* __restrict__ attn_o)
{
    __shared__ u16 pm_s[256][72];     // [f][d]
    __shared__ u16 q_s[64][72];       // [n][d]
    __shared__ u16 pq_s[64][264];     // [n][f]
    __shared__ u16 kv_s[64][264];     // [d][f]
    __shared__ float nrm_s[64];
    __shared__ float den_s[4][64];

    const int tid = threadIdx.x;
    const int lane = tid & 63, wave = tid >> 6;
    const int l16 = lane & 15, quad = lane >> 4;
    const int bh = blockIdx.y, b = bh / NH, h = bh % NH;
    const int n0 = blockIdx.x * 64;
    const int fbase = wave * 64;
    const int srow = tid >> 2, skof = (tid & 3) * 16;
    const float scale = 0.35355339059327373f;

#pragma unroll
    for (int j = 0; j < 8; ++j) {
        const int flat = j * 256 + tid;
        const int f = flat >> 3, o = (flat & 7) * 8;
        *(uint4*)&pm_s[f][o] = *(const uint4*)(pmb + f * 64 + o);
    }
#pragma unroll
    for (int j = 0; j < 8; ++j) {
        const int flat = j * 256 + tid;
        const int d = flat >> 5, o = (flat & 31) * 8;
        *(uint4*)&kv_s[d][o] = *(const uint4*)(kvT + ((size_t)bh * 64 + d) * 256 + o);
    }
    {
        const int n = n0 + srow;
        uint4 q0 = {0,0,0,0}, q1 = {0,0,0,0};
        if (n < NTOK) {
            const u16* qp = qkv + ((size_t)(b * NTOK + n)) * 576 + h * 64 + skof;
            q0 = *(const uint4*)qp; q1 = *(const uint4*)(qp + 8);
        }
        *(uint4*)&q_s[srow][skof]     = q0;
        *(uint4*)&q_s[srow][skof + 8] = q1;
        float sq = sqr8bf(q0) + sqr8bf(q1);
        sq += __shfl_xor(sq, 1);
        sq += __shfl_xor(sq, 2);
        if ((tid & 3) == 0) nrm_s[srow] = (n < NTOK) ? 0.5f * sq : 1e30f;
    }
    float ksr[4];
#pragma unroll
    for (int cf = 0; cf < 4; ++cf)
        ksr[cf] = ksum[(size_t)bh * 256 + fbase + cf * 16 + l16];
    __syncthreads();

    floatx4 pa[4][4];
#pragma unroll
    for (int i = 0; i < 4; ++i)
#pragma unroll
        for (int j = 0; j < 4; ++j) pa[i][j] = (floatx4){0.f,0.f,0.f,0.f};
#pragma unroll
    for (int ks = 0; ks < 2; ++ks) {
        short8 a[4], bb[4];
#pragma unroll
        for (int rf = 0; rf < 4; ++rf)
            a[rf] = *(const short8*)&q_s[rf*16 + l16][ks*32 + quad*8];
#pragma unroll
        for (int cf = 0; cf < 4; ++cf)
            bb[cf] = *(const short8*)&pm_s[fbase + cf*16 + l16][ks*32 + quad*8];
#pragma unroll
        for (int rf = 0; rf < 4; ++rf)
#pragma unroll
            for (int cf = 0; cf < 4; ++cf)
                pa[rf][cf] = __builtin_amdgcn_mfma_f32_16x16x32_bf16(a[rf], bb[cf], pa[rf][cf], 0, 0, 0);
    }

    float dpart[16];
#pragma unroll
    for (int i = 0; i < 16; ++i) dpart[i] = 0.f;
#pragma unroll
    for (int rf = 0; rf < 4; ++rf) {
        const int nl = rf * 16 + quad * 4;
        const float nr0 = nrm_s[nl + 0], nr1 = nrm_s[nl + 1];
        const float nr2 = nrm_s[nl + 2], nr3 = nrm_s[nl + 3];
#pragma unroll
        for (int cf = 0; cf < 4; ++cf) {
            const int f = fbase + cf * 16 + l16;
            const u16 b0 = f2bf(__expf(pa[rf][cf][0] - nr0) * scale);
            const u16 b1 = f2bf(__expf(pa[rf][cf][1] - nr1) * scale);
            const u16 b2 = f2bf(__expf(pa[rf][cf][2] - nr2) * scale);
            const u16 b3 = f2bf(__expf(pa[rf][cf][3] - nr3) * scale);
            pq_s[nl + 0][f] = b0;
            pq_s[nl + 1][f] = b1;
            pq_s[nl + 2][f] = b2;
            pq_s[nl + 3][f] = b3;
            dpart[rf*4 + 0] += bf2f(b0) * ksr[cf];
            dpart[rf*4 + 1] += bf2f(b1) * ksr[cf];
            dpart[rf*4 + 2] += bf2f(b2) * ksr[cf];
            dpart[rf*4 + 3] += bf2f(b3) * ksr[cf];
        }
    }
#pragma unroll
    for (int i = 0; i < 16; ++i) {
        float d = dpart[i];
        d += __shfl_xor(d, 1); d += __shfl_xor(d, 2);
        d += __shfl_xor(d, 4); d += __shfl_xor(d, 8);
        dpart[i] = d;
    }
    if (l16 == 0) {
#pragma unroll
        for (int rf = 0; rf < 4; ++rf)
#pragma unroll
            for (int reg = 0; reg < 4; ++reg)
                den_s[wave][rf*16 + quad*4 + reg] = dpart[rf*4 + reg];
    }
    __syncthreads();

    const int wr = wave & 1, wc = wave >> 1;
    floatx4 oc[2][2];
#pragma unroll
    for (int i = 0; i < 2; ++i)
#pragma unroll
        for (int j = 0; j < 2; ++j) oc[i][j] = (floatx4){0.f,0.f,0.f,0.f};
#pragma unroll
    for (int ks = 0; ks < 8; ++ks) {
        short8 a[2], bb[2];
#pragma unroll
        for (int rf = 0; rf < 2; ++rf)
            a[rf] = *(const short8*)&pq_s[wr*32 + rf*16 + l16][ks*32 + quad*8];
#pragma unroll
        for (int cf = 0; cf < 2; ++cf)
            bb[cf] = *(const short8*)&kv_s[wc*32 + cf*16 + l16][ks*32 + quad*8];
#pragma unroll
        for (int rf = 0; rf < 2; ++rf)
#pragma unroll
            for (int cf = 0; cf < 2; ++cf)
                oc[rf][cf] = __builtin_amdgcn_mfma_f32_16x16x32_bf16(a[rf], bb[cf], oc[rf][cf], 0, 0, 0);
    }

#pragma unroll
    for (int rf = 0; rf < 2; ++rf) {
#pragma unroll
        for (int reg = 0; reg < 4; ++reg) {
            const int nl = wr*32 + rf*16 + quad*4 + reg;
            const int gn = n0 + nl;
            if (gn >= NTOK) continue;
            const float di = 1.f / (den_s[0][nl] + den_s[1][nl] + den_s[2][nl] + den_s[3][nl]);
#pragma unroll
            for (int cf = 0; cf < 2; ++cf) {
                const int d = wc*32 + cf*16 + l16;
                attn_o[((size_t)(b * NTOK + gn)) * EMB + h * 64 + d] =
                    f2bf(oc[rf][cf][reg] * di);
            }
        }
    }
}

// ---------------- im2col (bf16 out) ----------------
__global__ void im2col_kernel(const float* __restrict__ x, u16* __restrict__ p, int total)
{
    const int i = blockIdx.x * 256 + threadIdx.x;
    if (i >= total) return;
    const int col = i % 768, row = i / 768;
    const int px = col & 15, py = (col >> 4) & 15, c = col >> 8;
    const int gx = row % 14, gy = (row / 14) % 14, b = row / 196;
    p[i] = f2bf(x[((size_t)(b * 3 + c) * 224 + gy * 16 + py) * 224 + gx * 16 + px]);
}

// ---------------- patch-embed finish ----------------
__global__ void embed_finish(const float* __restrict__ tok, const float* __restrict__ cls,
                             const float* __restrict__ pos, const float* __restrict__ w,
                             const float* __restrict__ b, float* __restrict__ h)
{
    const int wid = threadIdx.x >> 6, lane = threadIdx.x & 63;
    const int r = blockIdx.x * 4 + wid;
    if (r >= MTOT) return;
    const int bb = r / NTOK, t = r % NTOK;
    float* q = h + (size_t)r * EMB;
    if (t == 0) {
        q[lane]       = cls[lane]       + pos[lane];
        q[lane + 64]  = cls[lane + 64]  + pos[lane + 64];
        q[lane + 128] = cls[lane + 128] + pos[lane + 128];
        return;
    }
    const float* p = tok + ((size_t)bb * NPATCH + (t - 1)) * EMB;
    float x0 = p[lane], x1 = p[lane + 64], x2 = p[lane + 128];
    float s = x0 + x1 + x2;
#pragma unroll
    for (int off = 32; off; off >>= 1) s += __shfl_xor(s, off);
    const float mu = s * (1.f / 192.f);
    const float d0 = x0 - mu, d1 = x1 - mu, d2 = x2 - mu;
    float v = d0 * d0 + d1 * d1 + d2 * d2;
#pragma unroll
    for (int off = 32; off; off >>= 1) v += __shfl_xor(v, off);
    const float rstd = rsqrtf(v * (1.f / 192.f) + 1e-5f);
    const float* pr = pos + (size_t)t * EMB;
    q[lane]       = d0 * rstd * w[lane]       + b[lane]       + pr[lane];
    q[lane + 64]  = d1 * rstd * w[lane + 64]  + b[lane + 64]  + pr[lane + 64];
    q[lane + 128] = d2 * rstd * w[lane + 128] + b[lane + 128] + pr[lane + 128];
}

// ---------------- LayerNorm over 192; bf16 or fp32 out ----------------
__global__ void ln192(const float* __restrict__ in, int in_stride,
                      const float* __restrict__ w, const float* __restrict__ b,
                      u16* __restrict__ outb, float* __restrict__ outf, int rows)
{
    const int wid = threadIdx.x >> 6, lane = threadIdx.x & 63;
    const int r = blockIdx.x * 4 + wid;
    if (r >= rows) return;
    const float* p = in + (size_t)r * in_stride;
    float x0 = p[lane], x1 = p[lane + 64], x2 = p[lane + 128];
    float s = x0 + x1 + x2;
#pragma unroll
    for (int off = 32; off; off >>= 1) s += __shfl_xor(s, off);
    const float mu = s * (1.f / 192.f);
    const float d0 = x0 - mu, d1 = x1 - mu, d2 = x2 - mu;
    float v = d0 * d0 + d1 * d1 + d2 * d2;
#pragma unroll
    for (int off = 32; off; off >>= 1) v += __shfl_xor(v, off);
    const float rstd = rsqrtf(v * (1.f / 192.f) + 1e-5f);
    const float y0 = d0 * rstd * w[lane]       + b[lane];
    const float y1 = d1 * rstd * w[lane + 64]  + b[lane + 64];
    const float y2 = d2 * rstd * w[lane + 128] + b[lane + 128];
    if (outf) {
        float* q = outf + (size_t)r * EMB;
        q[lane] = y0; q[lane + 64] = y1; q[lane + 128] = y2;
    } else {
        u16* q = outb + (size_t)r * EMB;
        q[lane] = f2bf(y0); q[lane + 64] = f2bf(y1); q[lane + 128] = f2bf(y2);
    }
}

// ---------------- fp32 GEMM (head / exits only) ----------------
__global__ __launch_bounds__(256) void gemm_f32(
    const float* __restrict__ A, const float* __restrict__ Bm,
    const float* __restrict__ bias, float* __restrict__ C,
    int M, int N, int K)
{
    __shared__ float As[16][68];
    __shared__ float Bs[16][64];
    const int tid = threadIdx.x;
    const int tx = tid & 15, ty = tid >> 4;
    const int m0 = blockIdx.y * 64, n0 = blockIdx.x * 64;
    float acc[4][4] = {};

    for (int k0 = 0; k0 < K; k0 += 16) {
        {
            const int c = tid & 15, r4 = tid >> 4;
#pragma unroll
            for (int i = 0; i < 4; ++i) {
                const int r = r4 + i * 16, gm = m0 + r;
                As[c][r] = (gm < M) ? A[(size_t)gm * K + (k0 + c)] : 0.f;
            }
        }
        {
            const int cb = tid & 63, rb4 = tid >> 6;
#pragma unroll
            for (int i = 0; i < 4; ++i) {
                const int rb = rb4 + i * 4;
                const int gn = n0 + cb;
                Bs[rb][cb] = (gn < N) ? Bm[(size_t)(k0 + rb) * N + gn] : 0.f;
            }
        }
        __syncthreads();
#pragma unroll
        for (int kk = 0; kk < 16; ++kk) {
            const float4 av = *reinterpret_cast<const float4*>(&As[kk][ty * 4]);
            const float4 bv = *reinterpret_cast<const float4*>(&Bs[kk][tx * 4]);
            const float a_[4] = {av.x, av.y, av.z, av.w};
            const float b_[4] = {bv.x, bv.y, bv.z, bv.w};
#pragma unroll
            for (int i2 = 0; i2 < 4; ++i2)
#pragma unroll
                for (int j2 = 0; j2 < 4; ++j2)
                    acc[i2][j2] = fmaf(a_[i2], b_[j2], acc[i2][j2]);
        }
        __syncthreads();
    }

#pragma unroll
    for (int i = 0; i < 4; ++i) {
        const int gm = m0 + ty * 4 + i;
        if (gm >= M) continue;
#pragma unroll
        for (int j = 0; j < 4; ++j) {
            const int gn = n0 + tx * 4 + j;
            if (gn >= N) continue;
            C[(size_t)gm * N + gn] = acc[i][j] + bias[gn];
        }
    }
}

// ---------------- mean over tokens for exits (coalesced) ----------------
__global__ void pool_kernel(const float* __restrict__ h, float* __restrict__ pooled)
{
    __shared__ float red[192];
    const int b = blockIdx.x;
    const int slice = threadIdx.x / 192;       // 0..1  (384 threads)
    const int e = threadIdx.x % 192;
    float s = 0.f;
    for (int n = slice; n < NTOK; n += 2)
        s += h[((size_t)(b * NTOK + n)) * EMB + e];
    if (slice == 1) red[e] = s;
    __syncthreads();
    if (slice == 0)
        pooled[b * EMB + e] = (s + red[e]) * (1.f / 197.f);
}

// ---------------- host launch ----------------
extern "C" void kernel_launch(void* const* d_in, const int* in_sizes, int n_in,
                              void* d_out, int out_size, void* d_ws, size_t ws_size,
                              hipStream_t stream)
{
    const float* x          = (const float*)d_in[0];
    const float* patch_w    = (const float*)d_in[1];
    const float* patch_b    = (const float*)d_in[2];
    const float* pe_norm_w  = (const float*)d_in[3];
    const float* pe_norm_b  = (const float*)d_in[4];
    const float* cls_token  = (const float*)d_in[5];
    const float* pos_embed  = (const float*)d_in[6];
    const float* norm1_w    = (const float*)d_in[7];
    const float* norm1_b    = (const float*)d_in[8];
    const float* qkv_w      = (const float*)d_in[9];
    const float* qkv_b      = (const float*)d_in[10];
    const float* proj_mat   = (const float*)d_in[11];
    const float* attn_pw    = (const float*)d_in[12];
    const float* attn_pb    = (const float*)d_in[13];
    const float* norm2_w    = (const float*)d_in[14];
    const float* norm2_b    = (const float*)d_in[15];
    const float* fc1_w      = (const float*)d_in[16];
    const float* fc1_b      = (const float*)d_in[17];
    const float* fc2_w      = (const float*)d_in[18];
    const float* fc2_b      = (const float*)d_in[19];
    const float* exit_w     = (const float*)d_in[20];
    const float* exit_b     = (const float*)d_in[21];
    const float* fnorm_w    = (const float*)d_in[22];
    const float* fnorm_b    = (const float*)d_in[23];
    const float* head_w     = (const float*)d_in[24];
    const float* head_b     = (const float*)d_in[25];
    float* out = (float*)d_out;

    float* ws = (float*)d_ws;
    float* H     = ws + 0;                  // 12608*192 fp32
    u16*   QKVB  = (u16*)(ws + 2420736);    // 12608*576 bf16
    u16*   XLNB  = (u16*)(ws + 6051840);    // 12608*192 bf16
    u16*   KVT   = (u16*)(ws + 19968000);   // 192*64*256 bf16
    u16*   MIDB  = (u16*)(ws + 21540864);   // 12608*768 bf16
    u16*   ATNB  = (u16*)(ws + 26382336);   // 12608*192 bf16
    float* XLNF  = ws + 27592704;           // 64*192
    float* POOL  = ws + 27604992;           // 64*192
    float* KSUM  = ws + 27617280;           // 192*256
    u16*   QKVWT = (u16*)(ws + 27666432);   // 12*576*192 bf16
    u16*   APWT  = (u16*)(ws + 28329984);   // 12*192*192 bf16
    u16*   F1WT  = (u16*)(ws + 28551168);   // 12*768*192 bf16
    u16*   F2WT  = (u16*)(ws + 29435904);   // 12*192*768 bf16
    u16*   PATWB = (u16*)(ws + 30320640);   // 192*768 bf16
    u16*   PMB   = (u16*)(ws + 30394368);   // 12*256*64 bf16
    u16*   P_IMB = MIDB;                    // im2col alias (prologue only)
    float* TOK   = (float*)QKVB;            // patch tokens alias (prologue only)

    if (ws_size < (size_t)30492672 * sizeof(float)) return;

    // ---- weight prep ----
    cvt_bf16<<<(147456 + 255) / 256, 256, 0, stream>>>(patch_w, PATWB, 147456);
    cvt_bf16<<<(196608 + 255) / 256, 256, 0, stream>>>(proj_mat, PMB, 196608);
    tr_bf16_t<<<dim3(18, 6, 12), 256, 0, stream>>>(qkv_w,   QKVWT, 192, 576);
    tr_bf16_t<<<dim3(6, 6, 12),  256, 0, stream>>>(attn_pw, APWT,  192, 192);
    tr_bf16_t<<<dim3(24, 6, 12), 256, 0, stream>>>(fc1_w,   F1WT,  192, 768);
    tr_bf16_t<<<dim3(6, 24, 12), 256, 0, stream>>>(fc2_w,   F2WT,  768, 192);

    // ---- patch embed ----
    im2col_kernel<<<(MPAT * 768 + 255) / 256, 256, 0, stream>>>(x, P_IMB, MPAT * 768);
    gemm_bf16<<<294, 256, 0, stream>>>(P_IMB, PATWB, patch_b,
                                       TOK, nullptr, MPAT, EMB, 768, 0, 3);
    embed_finish<<<(MTOT + 3) / 4, 256, 0, stream>>>(TOK, cls_token, pos_embed,
                                                     pe_norm_w, pe_norm_b, H);
    ln192<<<(MTOT + 3) / 4, 256, 0, stream>>>(H, EMB, norm1_w, norm1_b,
                                              XLNB, nullptr, MTOT);

    // ---- transformer layers ----
    for (int i = 0; i < 12; ++i) {
        const u16* qwt  = QKVWT + (size_t)i * 576 * 192;
        const u16* pwt  = APWT  + (size_t)i * 192 * 192;
        const u16* f1wt = F1WT  + (size_t)i * 768 * 192;
        const u16* f2wt = F2WT  + (size_t)i * 192 * 768;
        const u16* pmb  = PMB   + (size_t)i * 256 * 64;
        const float* qb  = qkv_b   + (size_t)i * 576;
        const float* pb  = attn_pb + (size_t)i * 192;
        const float* f1b = fc1_b   + (size_t)i * 768;
        const float* f2b = fc2_b   + (size_t)i * 192;

        gemm_bf16<<<891, 256, 0, stream>>>(XLNB, qwt, qb,
                                           nullptr, QKVB, MTOT, 576, 192, 3, 9);
        attn_pkv<<<dim3(BHT), 256, 0, stream>>>(QKVB, pmb, KVT, KSUM);
        attn_out<<<dim3(4, BHT), 256, 0, stream>>>(QKVB, pmb, KVT, KSUM, ATNB);
        gemm_ln<<<197, 256, 0, stream>>>(ATNB, pwt, pb,
                                         norm2_w + (size_t)i * EMB, norm2_b + (size_t)i * EMB,
                                         H, XLNB, EMB);
        gemm_bf16<<<1188, 256, 0, stream>>>(XLNB, f1wt, f1b,
                                            nullptr, MIDB, MTOT, MLPD, 192, 2, 12);
        const float* nw = (i < 11) ? norm1_w + (size_t)(i + 1) * EMB : nullptr;
        const float* nb = (i < 11) ? norm1_b + (size_t)(i + 1) * EMB : nullptr;
        gemm_ln<<<197, 256, 0, stream>>>(MIDB, f2wt, f2b, nw, nb, H, XLNB, MLPD);

        const int e = (i == 3) ? 0 : (i == 7) ? 1 : (i == 11) ? 2 : -1;
        if (e >= 0) {
            pool_kernel<<<BB, 384, 0, stream>>>(H, POOL);
            gemm_f32<<<dim3(16, 1), 256, 0, stream>>>(POOL, exit_w + (size_t)e * 192 * 1000,
                                                      exit_b + (size_t)e * 1000,
                                                      out + (size_t)(1 + e) * BB * NCLS,
                                                      BB, NCLS, EMB);
        }
    }

    // ---- head ----
    ln192<<<(BB + 3) / 4, 256, 0, stream>>>(H, NTOK * EMB, fnorm_w, fnorm_b,
                                            nullptr, XLNF, BB);
    gemm_f32<<<dim3(16, 1), 256, 0, stream>>>(XLNF, head_w, head_b, out, BB, NCLS, EMB);
}

// Round 5
// 1390.676 us; speedup vs baseline: 1.3727x; 1.1075x over previous
//
#include <hip/hip_runtime.h>
#include <math.h>

typedef unsigned short u16;
typedef unsigned int u32;
typedef __attribute__((ext_vector_type(8))) short short8;
typedef __attribute__((ext_vector_type(4))) float floatx4;

// ---------------- problem constants ----------------
#define BB 64
#define NTOK 197
#define NPATCH 196
#define EMB 192
#define NH 3
#define HD 64
#define FEAT 256
#define MLPD 768
#define NCLS 1000
#define MTOT (BB*NTOK)      // 12608
#define MPAT (BB*NPATCH)    // 12544
#define BHT (BB*NH)         // 192

// ---------------- bf16 helpers ----------------
__device__ __forceinline__ u16 f2bf(float x) {
    u32 u = __builtin_bit_cast(u32, x);
    u32 r = u + 0x7FFFu + ((u >> 16) & 1u);
    return (u16)(r >> 16);
}
__device__ __forceinline__ float bf2f(u16 u) {
    return __builtin_bit_cast(float, (u32)u << 16);
}
__device__ __forceinline__ float sqr8bf(uint4 v) {
    float s = 0.f;
    float t;
    t = bf2f((u16)(v.x & 0xffff)); s += t*t;  t = bf2f((u16)(v.x >> 16)); s += t*t;
    t = bf2f((u16)(v.y & 0xffff)); s += t*t;  t = bf2f((u16)(v.y >> 16)); s += t*t;
    t = bf2f((u16)(v.z & 0xffff)); s += t*t;  t = bf2f((u16)(v.z >> 16)); s += t*t;
    t = bf2f((u16)(v.w & 0xffff)); s += t*t;  t = bf2f((u16)(v.w >> 16)); s += t*t;
    return s;
}

// ---------------- weight prep ----------------
__global__ void cvt_bf16(const float* __restrict__ in, u16* __restrict__ out, int n)
{
    const int i = blockIdx.x * 256 + threadIdx.x;
    if (i < n) out[i] = f2bf(in[i]);
}

// scalar transpose (prologue-only, small tensors): [L][R][C] -> [L][C][R] bf16
__global__ void tr_bf16(const float* __restrict__ in, u16* __restrict__ out,
                        int R, int C, int total)
{
    const int i = blockIdx.x * 256 + threadIdx.x;
    if (i >= total) return;
    const int r = i % R;
    const int c = (i / R) % C;
    const int l = i / (R * C);
    out[i] = f2bf(in[((size_t)l * R + r) * C + c]);
}

// in [L][R][C] fp32 -> out [L][C][R] bf16, coalesced via LDS 32x32 tiles
__global__ void tr_bf16_t(const float* __restrict__ in, u16* __restrict__ out,
                          int R, int C)
{
    __shared__ u16 t[32][33];
    const int l = blockIdx.z;
    const int c0 = blockIdx.x * 32, r0 = blockIdx.y * 32;
    const int tx = threadIdx.x & 31, ty = threadIdx.x >> 5;   // ty 0..7
    const float* ip = in + ((size_t)l * R + r0) * C + c0;
#pragma unroll
    for (int j = 0; j < 4; ++j)
        t[ty + j*8][tx] = f2bf(ip[(size_t)(ty + j*8) * C + tx]);
    __syncthreads();
    u16* op = out + ((size_t)l * C + c0) * R + r0;
#pragma unroll
    for (int j = 0; j < 4; ++j)
        op[(size_t)(ty + j*8) * R + tx] = t[tx][ty + j*8];
}

// ================= MFMA bf16 GEMM, 128x64 tile, XCD-swizzled =================
// C[M,N] = A[M,K] @ Bt[N,K]^T + bias.  Grid = 1D (mtiles*ntx) with bijective
// XCD-chunked swizzle (each XCD owns a contiguous m-range -> A-strip L2 reuse).
// mode 0: fp32 out ; mode 2: gelu->bf16 ; mode 3: bf16
__global__ __launch_bounds__(256) void gemm_bf16(
    const u16* __restrict__ A, const u16* __restrict__ Bt,
    const float* __restrict__ bias,
    float* __restrict__ Cf, u16* __restrict__ Cb,
    int M, int N, int K, int mode, int ntx)
{
    __shared__ u16 As[128][72];
    __shared__ u16 Bs[64][72];
    const int tid = threadIdx.x;
    const int lane = tid & 63, wave = tid >> 6;
    const int l16 = lane & 15, quad = lane >> 4;
    const int nwg = gridDim.x;
    const int q = nwg >> 3, r = nwg & 7;
    const int xcd = blockIdx.x & 7, jj = blockIdx.x >> 3;
    const int wg = (xcd < r ? xcd * (q + 1) : r * (q + 1) + (xcd - r) * q) + jj;
    const int m0 = (wg / ntx) * 128, n0 = (wg % ntx) * 64;
    const int arow = tid >> 1, aof = (tid & 1) * 32;
    const int brow = tid >> 2, bof = (tid & 3) * 16;

    floatx4 acc[2][4];
#pragma unroll
    for (int i = 0; i < 2; ++i)
#pragma unroll
        for (int j = 0; j < 4; ++j) acc[i][j] = (floatx4){0.f,0.f,0.f,0.f};

    const int gmA = m0 + arow;
    const bool aok = (gmA < M);
    const u16* ap = A + (size_t)gmA * K + aof;
    const u16* bp = Bt + (size_t)(n0 + brow) * K + bof;

    for (int k0 = 0; k0 < K; k0 += 64) {
        uint4 a0 = {0,0,0,0}, a1 = {0,0,0,0}, a2 = {0,0,0,0}, a3 = {0,0,0,0};
        if (aok) {
            a0 = *(const uint4*)(ap + k0);
            a1 = *(const uint4*)(ap + k0 + 8);
            a2 = *(const uint4*)(ap + k0 + 16);
            a3 = *(const uint4*)(ap + k0 + 24);
        }
        const uint4 b0 = *(const uint4*)(bp + k0);
        const uint4 b1 = *(const uint4*)(bp + k0 + 8);
        if (k0) __syncthreads();
        *(uint4*)&As[arow][aof]      = a0;
        *(uint4*)&As[arow][aof + 8]  = a1;
        *(uint4*)&As[arow][aof + 16] = a2;
        *(uint4*)&As[arow][aof + 24] = a3;
        *(uint4*)&Bs[brow][bof]      = b0;
        *(uint4*)&Bs[brow][bof + 8]  = b1;
        __syncthreads();
#pragma unroll
        for (int ks = 0; ks < 2; ++ks) {
            short8 af[2], bf[4];
#pragma unroll
            for (int rf = 0; rf < 2; ++rf)
                af[rf] = *(const short8*)&As[wave*32 + rf*16 + l16][ks*32 + quad*8];
#pragma unroll
            for (int cf = 0; cf < 4; ++cf)
                bf[cf] = *(const short8*)&Bs[cf*16 + l16][ks*32 + quad*8];
#pragma unroll
            for (int rf = 0; rf < 2; ++rf)
#pragma unroll
                for (int cf = 0; cf < 4; ++cf)
                    acc[rf][cf] = __builtin_amdgcn_mfma_f32_16x16x32_bf16(af[rf], bf[cf], acc[rf][cf], 0, 0, 0);
        }
    }

    if (mode == 0) {
        const int rbase = m0 + wave * 32 + quad * 4;
        const int cbase = n0 + l16;
#pragma unroll
        for (int rf = 0; rf < 2; ++rf) {
#pragma unroll
            for (int reg = 0; reg < 4; ++reg) {
                const int gm = rbase + rf * 16 + reg;
                if (gm >= M) continue;
#pragma unroll
                for (int cf = 0; cf < 4; ++cf) {
                    const int gn = cbase + cf * 16;
                    Cf[(size_t)gm * N + gn] = acc[rf][cf][reg] + bias[gn];
                }
            }
        }
        return;
    }

    // bf16 epilogue: bias(+gelu) -> swizzled LDS tile -> coalesced uint4 stores
    __syncthreads();
#pragma unroll
    for (int rf = 0; rf < 2; ++rf) {
#pragma unroll
        for (int cf = 0; cf < 4; ++cf) {
            const int lc = cf * 16 + l16;
            const float bia = bias[n0 + lc];
#pragma unroll
            for (int reg = 0; reg < 4; ++reg) {
                const int lr = wave * 32 + rf * 16 + quad * 4 + reg;
                float v = acc[rf][cf][reg] + bia;
                if (mode == 2)
                    v = 0.5f * v * (1.f + erff(v * 0.70710678118654752f));
                const int phys = (((lc >> 3) ^ (lr & 7)) << 3) | (lc & 7);
                As[lr][phys] = f2bf(v);
            }
        }
    }
    __syncthreads();
#pragma unroll
    for (int it = 0; it < 4; ++it) {
        const int idx = it * 256 + tid;
        const int row = idx >> 3, c8 = idx & 7;
        const int pc8 = c8 ^ (row & 7);
        const uint4 val = *(const uint4*)&As[row][pc8 * 8];
        const int gm = m0 + row;
        if (gm < M)
            *(uint4*)&Cb[(size_t)gm * N + n0 + c8 * 8] = val;
    }
}

// ================= fused GEMM(+bias+residual) + LayerNorm, 32-row tile ========
// Tile 32 x 192 (full row), M = 12608 = 394*32.
__global__ __launch_bounds__(256) void gemm_ln(
    const u16* __restrict__ A, const u16* __restrict__ Bt,
    const float* __restrict__ bias,
    const float* __restrict__ lnw, const float* __restrict__ lnb,
    float* __restrict__ H, u16* __restrict__ outb, int K)
{
    __shared__ u16 As[32][72];
    __shared__ u16 Bs[192][72];
    __shared__ float red_s[2][32][2];
    const int tid = threadIdx.x;
    const int lane = tid & 63, wave = tid >> 6;
    const int wr = wave & 1;          // row frag (16 rows)
    const int wc = wave >> 1;         // col half (96 cols)
    const int l16 = lane & 15, quad = lane >> 4;
    const int m0 = blockIdx.x * 32;
    const int srowA = tid >> 3, skofA = (tid & 7) * 8;
    const int srow = tid >> 2, skof = (tid & 3) * 16;

    floatx4 acc[6];
#pragma unroll
    for (int j = 0; j < 6; ++j) acc[j] = (floatx4){0.f,0.f,0.f,0.f};

    const u16* ap = A + (size_t)(m0 + srowA) * K + skofA;
    const u16* bp = Bt + (size_t)srow * K + skof;
    const size_t bstep = (size_t)64 * K;

    for (int k0 = 0; k0 < K; k0 += 64) {
        const uint4 a0 = *(const uint4*)(ap + k0);
        const uint4 b0 = *(const uint4*)(bp + k0);
        const uint4 b1 = *(const uint4*)(bp + k0 + 8);
        const uint4 b2 = *(const uint4*)(bp + bstep + k0);
        const uint4 b3 = *(const uint4*)(bp + bstep + k0 + 8);
        const uint4 b4 = *(const uint4*)(bp + 2*bstep + k0);
        const uint4 b5 = *(const uint4*)(bp + 2*bstep + k0 + 8);
        if (k0) __syncthreads();
        *(uint4*)&As[srowA][skofA]         = a0;
        *(uint4*)&Bs[srow][skof]           = b0;
        *(uint4*)&Bs[srow][skof + 8]       = b1;
        *(uint4*)&Bs[srow + 64][skof]      = b2;
        *(uint4*)&Bs[srow + 64][skof + 8]  = b3;
        *(uint4*)&Bs[srow + 128][skof]     = b4;
        *(uint4*)&Bs[srow + 128][skof + 8] = b5;
        __syncthreads();
#pragma unroll
        for (int ks = 0; ks < 2; ++ks) {
            const short8 af = *(const short8*)&As[wr*16 + l16][ks*32 + quad*8];
            short8 bf[6];
#pragma unroll
            for (int cf = 0; cf < 6; ++cf)
                bf[cf] = *(const short8*)&Bs[wc*96 + cf*16 + l16][ks*32 + quad*8];
#pragma unroll
            for (int cf = 0; cf < 6; ++cf)
                acc[cf] = __builtin_amdgcn_mfma_f32_16x16x32_bf16(af, bf[cf], acc[cf], 0, 0, 0);
        }
    }

    // epilogue: bias + residual -> H (fp32), accumulate row sum / sumsq
    float s_[4], q_[4];
#pragma unroll
    for (int reg = 0; reg < 4; ++reg) { s_[reg] = 0.f; q_[reg] = 0.f; }

#pragma unroll
    for (int cf = 0; cf < 6; ++cf) {
        const int gn = wc * 96 + cf * 16 + l16;
        const float bia = bias[gn];
#pragma unroll
        for (int reg = 0; reg < 4; ++reg) {
            const int gm = m0 + wr * 16 + quad * 4 + reg;
            float v = acc[cf][reg] + bia + H[(size_t)gm * EMB + gn];
            H[(size_t)gm * EMB + gn] = v;
            acc[cf][reg] = v;
            s_[reg] += v;
            q_[reg] += v * v;
        }
    }

    if (lnw) {
#pragma unroll
        for (int reg = 0; reg < 4; ++reg) {
            float s = s_[reg], q = q_[reg];
            s += __shfl_xor(s, 1); q += __shfl_xor(q, 1);
            s += __shfl_xor(s, 2); q += __shfl_xor(q, 2);
            s += __shfl_xor(s, 4); q += __shfl_xor(q, 4);
            s += __shfl_xor(s, 8); q += __shfl_xor(q, 8);
            if (l16 == 0) {
                const int rl = wr * 16 + quad * 4 + reg;
                red_s[wc][rl][0] = s;
                red_s[wc][rl][1] = q;
            }
        }
        __syncthreads();
#pragma unroll
        for (int reg = 0; reg < 4; ++reg) {
            const int rl = wr * 16 + quad * 4 + reg;
            const float ts = red_s[0][rl][0] + red_s[1][rl][0];
            const float tq = red_s[0][rl][1] + red_s[1][rl][1];
            const float mu = ts * (1.f / 192.f);
            const float var = tq * (1.f / 192.f) - mu * mu;
            const float rstd = rsqrtf(fmaxf(var, 0.f) + 1e-5f);
            const int gm = m0 + rl;
#pragma unroll
            for (int cf = 0; cf < 6; ++cf) {
                const int gn = wc * 96 + cf * 16 + l16;
                const float y = (acc[cf][reg] - mu) * rstd * lnw[gn] + lnb[gn];
                outb[(size_t)gm * EMB + gn] = f2bf(y);
            }
        }
    }
}

// ================= fused performer attention, stage 1 (f-split) ==============
// Grid (4, BHT): block (fq, bh) computes kvT/ksum for f-range fq*64..fq*64+63.
// Each wave owns a 16-f strip (writes & reads only its own pkT rows).
__global__ __launch_bounds__(256) void attn_pkv(
    const u16* __restrict__ qkv, const u16* __restrict__ pmb,
    u16* __restrict__ kvT, float* __restrict__ ksum)
{
    __shared__ u16 pm_s[64][72];      // [f_loc][d]
    __shared__ u16 kt_s[64][72];      // [n][d] tile
    __shared__ u16 vT_s[64][72];      // [d][n] tile
    __shared__ u16 pkT_s[64][72];     // [f_loc][n] tile
    __shared__ float nrm_s[64];
    __shared__ float ksum_s[64];

    const int tid = threadIdx.x;
    const int lane = tid & 63, wave = tid >> 6;
    const int l16 = lane & 15, quad = lane >> 4;
    const int fq = blockIdx.x, bh = blockIdx.y, b = bh / NH, h = bh % NH;
    const int fwave = wave * 16;
    const int srow = tid >> 2, skof = (tid & 3) * 16;
    const float scale = 0.35355339059327373f;

    // pm rows for this block's f-range: 64 x 64 bf16
#pragma unroll
    for (int j = 0; j < 2; ++j) {
        const int flat = j * 256 + tid;
        const int row = flat >> 3, o = (flat & 7) * 8;
        *(uint4*)&pm_s[row][o] = *(const uint4*)(pmb + (size_t)(fq * 64 + row) * 64 + o);
    }
    if (tid < 64) ksum_s[tid] = 0.f;

    floatx4 kv[4];
#pragma unroll
    for (int i = 0; i < 4; ++i) kv[i] = (floatx4){0.f,0.f,0.f,0.f};

    uint4 k0v = {0,0,0,0}, k1v = {0,0,0,0}, v0v = {0,0,0,0}, v1v = {0,0,0,0};
    {
        const u16* kp = qkv + ((size_t)(b * NTOK + srow)) * 576 + 192 + h * 64 + skof;
        k0v = *(const uint4*)kp; k1v = *(const uint4*)(kp + 8);
        v0v = *(const uint4*)(kp + 192); v1v = *(const uint4*)(kp + 200);
    }

    for (int t = 0; t < 4; ++t) {
        const int ncur = t * 64 + srow;
        if (t) __syncthreads();
        *(uint4*)&kt_s[srow][skof]     = k0v;
        *(uint4*)&kt_s[srow][skof + 8] = k1v;
        {
            u16 vv[16];
            vv[0]=(u16)(v0v.x&0xffff);  vv[1]=(u16)(v0v.x>>16);
            vv[2]=(u16)(v0v.y&0xffff);  vv[3]=(u16)(v0v.y>>16);
            vv[4]=(u16)(v0v.z&0xffff);  vv[5]=(u16)(v0v.z>>16);
            vv[6]=(u16)(v0v.w&0xffff);  vv[7]=(u16)(v0v.w>>16);
            vv[8]=(u16)(v1v.x&0xffff);  vv[9]=(u16)(v1v.x>>16);
            vv[10]=(u16)(v1v.y&0xffff); vv[11]=(u16)(v1v.y>>16);
            vv[12]=(u16)(v1v.z&0xffff); vv[13]=(u16)(v1v.z>>16);
            vv[14]=(u16)(v1v.w&0xffff); vv[15]=(u16)(v1v.w>>16);
#pragma unroll
            for (int j = 0; j < 16; ++j) vT_s[skof + j][srow] = vv[j];
        }
        float sq = sqr8bf(k0v) + sqr8bf(k1v);
        sq += __shfl_xor(sq, 1);
        sq += __shfl_xor(sq, 2);
        if ((tid & 3) == 0) nrm_s[srow] = (ncur < NTOK) ? 0.5f * sq : 1e30f;
        __syncthreads();

        if (t < 3) {
            const int n = (t + 1) * 64 + srow;
            k0v = (uint4){0,0,0,0}; k1v = (uint4){0,0,0,0};
            v0v = (uint4){0,0,0,0}; v1v = (uint4){0,0,0,0};
            if (n < NTOK) {
                const u16* kp = qkv + ((size_t)(b * NTOK + n)) * 576 + 192 + h * 64 + skof;
                k0v = *(const uint4*)kp; k1v = *(const uint4*)(kp + 8);
                v0v = *(const uint4*)(kp + 192); v1v = *(const uint4*)(kp + 200);
            }
        }

        // pk: C[n 64][f 16-per-wave]
        floatx4 pa[4];
#pragma unroll
        for (int i = 0; i < 4; ++i) pa[i] = (floatx4){0.f,0.f,0.f,0.f};
#pragma unroll
        for (int ks = 0; ks < 2; ++ks) {
            const short8 bpm = *(const short8*)&pm_s[fwave + l16][ks*32 + quad*8];
#pragma unroll
            for (int rf = 0; rf < 4; ++rf) {
                const short8 a = *(const short8*)&kt_s[rf*16 + l16][ks*32 + quad*8];
                pa[rf] = __builtin_amdgcn_mfma_f32_16x16x32_bf16(a, bpm, pa[rf], 0, 0, 0);
            }
        }

        // exp epilogue -> pkT_s [f_loc][n] (own rows only), ksum partial
        float ksp = 0.f;
        const int floc = fwave + l16;
#pragma unroll
        for (int rf = 0; rf < 4; ++rf) {
            const int nl = rf * 16 + quad * 4;
            const u16 b0 = f2bf(__expf(pa[rf][0] - nrm_s[nl + 0]) * scale);
            const u16 b1 = f2bf(__expf(pa[rf][1] - nrm_s[nl + 1]) * scale);
            const u16 b2 = f2bf(__expf(pa[rf][2] - nrm_s[nl + 2]) * scale);
            const u16 b3 = f2bf(__expf(pa[rf][3] - nrm_s[nl + 3]) * scale);
            ksp += bf2f(b0) + bf2f(b1) + bf2f(b2) + bf2f(b3);
            *(u32*)&pkT_s[floc][nl]     = (u32)b0 | ((u32)b1 << 16);
            *(u32*)&pkT_s[floc][nl + 2] = (u32)b2 | ((u32)b3 << 16);
        }
        {
            float v = ksp;
            v += __shfl_xor(v, 16);
            v += __shfl_xor(v, 32);
            if (quad == 0) ksum_s[floc] += v;
        }

        // kv accumulate: C[d 64][f 16-per-wave]
#pragma unroll
        for (int ks = 0; ks < 2; ++ks) {
            const short8 bpk = *(const short8*)&pkT_s[fwave + l16][ks*32 + quad*8];
#pragma unroll
            for (int rf = 0; rf < 4; ++rf) {
                const short8 a = *(const short8*)&vT_s[rf*16 + l16][ks*32 + quad*8];
                kv[rf] = __builtin_amdgcn_mfma_f32_16x16x32_bf16(a, bpk, kv[rf], 0, 0, 0);
            }
        }
    }

    __syncthreads();
    if (tid < 64) ksum[(size_t)bh * 256 + fq * 64 + tid] = ksum_s[tid];
    const int fg = fq * 64 + fwave + l16;
#pragma unroll
    for (int rf = 0; rf < 4; ++rf) {
#pragma unroll
        for (int reg = 0; reg < 4; ++reg) {
            const int d = rf * 16 + quad * 4 + reg;
            kvT[((size_t)bh * 64 + d) * 256 + fg] = f2bf(kv[rf][reg]);
        }
    }
}

// ================= fused performer attention, stage 2 =====================
__global__ __launch_bounds__(256) void attn_out(
    const u16* __restrict__ qkv, const u16* __restrict__ pmb,
    const u16* __restrict__ kvT, const float* __restrict__ ksum,
    u16* __restrict__ attn_o)
{
    __shared__ u16 pm_s[256][72];     // [f][d]
    __shared__ u16 q_s[64][72];       // [n][d]
    __shared__ u16 pq_s[64][264];     // [n][f]
    __shared__ u16 kv_s[64][264];     // [d][f]
    __shared__ float nrm_s[64];
    __shared__ float den_s[4][64];

    const int tid = threadIdx.x;
    const int lane = tid & 63, wave = tid >> 6;
    const int l16 = lane & 15, quad = lane >> 4;
    const int bh = blockIdx.y, b = bh / NH, h = bh % NH;
    const int n0 = blockIdx.x * 64;
    const int fbase = wave * 64;
    const int srow = tid >> 2, skof = (tid & 3) * 16;
    const float scale = 0.35355339059327373f;

#pragma unroll
    for (int j = 0; j < 8; ++j) {
        const int flat = j * 256 + tid;
        const int f = flat >> 3, o = (flat & 7) * 8;
        *(uint4*)&pm_s[f][o] = *(const uint4*)(pmb + f * 64 + o);
    }
#pragma unroll
    for (int j = 0; j < 8; ++j) {
        const int flat = j * 256 + tid;
        const int d = flat >> 5, o = (flat & 31) * 8;
        *(uint4*)&kv_s[d][o] = *(const uint4*)(kvT + ((size_t)bh * 64 + d) * 256 + o);
    }
    {
        const int n = n0 + srow;
        uint4 q0 = {0,0,0,0}, q1 = {0,0,0,0};
        if (n < NTOK) {
            const u16* qp = qkv + ((size_t)(b * NTOK + n)) * 576 + h * 64 + skof;
            q0 = *(const uint4*)qp; q1 = *(const uint4*)(qp + 8);
        }
        *(uint4*)&q_s[srow][skof]     = q0;
        *(uint4*)&q_s[srow][skof + 8] = q1;
        float sq = sqr8bf(q0) + sqr8bf(q1);
        sq += __shfl_xor(sq, 1);
        sq += __shfl_xor(sq, 2);
        if ((tid & 3) == 0) nrm_s[srow] = (n < NTOK) ? 0.5f * sq : 1e30f;
    }
    float ksr[4];
#pragma unroll
    for (int cf = 0; cf < 4; ++cf)
        ksr[cf] = ksum[(size_t)bh * 256 + fbase + cf * 16 + l16];
    __syncthreads();

    floatx4 pa[4][4];
#pragma unroll
    for (int i = 0; i < 4; ++i)
#pragma unroll
        for (int j = 0; j < 4; ++j) pa[i][j] = (floatx4){0.f,0.f,0.f,0.f};
#pragma unroll
    for (int ks = 0; ks < 2; ++ks) {
        short8 a[4], bb[4];
#pragma unroll
        for (int rf = 0; rf < 4; ++rf)
            a[rf] = *(const short8*)&q_s[rf*16 + l16][ks*32 + quad*8];
#pragma unroll
        for (int cf = 0; cf < 4; ++cf)
            bb[cf] = *(const short8*)&pm_s[fbase + cf*16 + l16][ks*32 + quad*8];
#pragma unroll
        for (int rf = 0; rf < 4; ++rf)
#pragma unroll
            for (int cf = 0; cf < 4; ++cf)
                pa[rf][cf] = __builtin_amdgcn_mfma_f32_16x16x32_bf16(a[rf], bb[cf], pa[rf][cf], 0, 0, 0);
    }

    float dpart[16];
#pragma unroll
    for (int i = 0; i < 16; ++i) dpart[i] = 0.f;
#pragma unroll
    for (int rf = 0; rf < 4; ++rf) {
        const int nl = rf * 16 + quad * 4;
        const float nr0 = nrm_s[nl + 0], nr1 = nrm_s[nl + 1];
        const float nr2 = nrm_s[nl + 2], nr3 = nrm_s[nl + 3];
#pragma unroll
        for (int cf = 0; cf < 4; ++cf) {
            const int f = fbase + cf * 16 + l16;
            const u16 b0 = f2bf(__expf(pa[rf][cf][0] - nr0) * scale);
            const u16 b1 = f2bf(__expf(pa[rf][cf][1] - nr1) * scale);
            const u16 b2 = f2bf(__expf(pa[rf][cf][2] - nr2) * scale);
            const u16 b3 = f2bf(__expf(pa[rf][cf][3] - nr3) * scale);
            pq_s[nl + 0][f] = b0;
            pq_s[nl + 1][f] = b1;
            pq_s[nl + 2][f] = b2;
            pq_s[nl + 3][f] = b3;
            dpart[rf*4 + 0] += bf2f(b0) * ksr[cf];
            dpart[rf*4 + 1] += bf2f(b1) * ksr[cf];
            dpart[rf*4 + 2] += bf2f(b2) * ksr[cf];
            dpart[rf*4 + 3] += bf2f(b3) * ksr[cf];
        }
    }
#pragma unroll
    for (int i = 0; i < 16; ++i) {
        float d = dpart[i];
        d += __shfl_xor(d, 1); d += __shfl_xor(d, 2);
        d += __shfl_xor(d, 4); d += __shfl_xor(d, 8);
        dpart[i] = d;
    }
    if (l16 == 0) {
#pragma unroll
        for (int rf = 0; rf < 4; ++rf)
#pragma unroll
            for (int reg = 0; reg < 4; ++reg)
                den_s[wave][rf*16 + quad*4 + reg] = dpart[rf*4 + reg];
    }
    __syncthreads();

    const int wr = wave & 1, wc = wave >> 1;
    floatx4 oc[2][2];
#pragma unroll
    for (int i = 0; i < 2; ++i)
#pragma unroll
        for (int j = 0; j < 2; ++j) oc[i][j] = (floatx4){0.f,0.f,0.f,0.f};
#pragma unroll
    for (int ks = 0; ks < 8; ++ks) {
        short8 a[2], bb[2];
#pragma unroll
        for (int rf = 0; rf < 2; ++rf)
            a[rf] = *(const short8*)&pq_s[wr*32 + rf*16 + l16][ks*32 + quad*8];
#pragma unroll
        for (int cf = 0; cf < 2; ++cf)
            bb[cf] = *(const short8*)&kv_s[wc*32 + cf*16 + l16][ks*32 + quad*8];
#pragma unroll
        for (int rf = 0; rf < 2; ++rf)
#pragma unroll
            for (int cf = 0; cf < 2; ++cf)
                oc[rf][cf] = __builtin_amdgcn_mfma_f32_16x16x32_bf16(a[rf], bb[cf], oc[rf][cf], 0, 0, 0);
    }

#pragma unroll
    for (int rf = 0; rf < 2; ++rf) {
#pragma unroll
        for (int reg = 0; reg < 4; ++reg) {
            const int nl = wr*32 + rf*16 + quad*4 + reg;
            const int gn = n0 + nl;
            if (gn >= NTOK) continue;
            const float di = 1.f / (den_s[0][nl] + den_s[1][nl] + den_s[2][nl] + den_s[3][nl]);
#pragma unroll
            for (int cf = 0; cf < 2; ++cf) {
                const int d = wc*32 + cf*16 + l16;
                attn_o[((size_t)(b * NTOK + gn)) * EMB + h * 64 + d] =
                    f2bf(oc[rf][cf][reg] * di);
            }
        }
    }
}

// ---------------- im2col (bf16 out) ----------------
__global__ void im2col_kernel(const float* __restrict__ x, u16* __restrict__ p, int total)
{
    const int i = blockIdx.x * 256 + threadIdx.x;
    if (i >= total) return;
    const int col = i % 768, row = i / 768;
    const int px = col & 15, py = (col >> 4) & 15, c = col >> 8;
    const int gx = row % 14, gy = (row / 14) % 14, b = row / 196;
    p[i] = f2bf(x[((size_t)(b * 3 + c) * 224 + gy * 16 + py) * 224 + gx * 16 + px]);
}

// ---------------- patch-embed finish + fused norm1 LN of layer 0 ----------------
__global__ void embed_finish(const float* __restrict__ tok, const float* __restrict__ cls,
                             const float* __restrict__ pos, const float* __restrict__ w,
                             const float* __restrict__ b,
                             const float* __restrict__ n1w, const float* __restrict__ n1b,
                             float* __restrict__ h, u16* __restrict__ outb)
{
    const int wid = threadIdx.x >> 6, lane = threadIdx.x & 63;
    const int r = blockIdx.x * 4 + wid;
    if (r >= MTOT) return;
    const int bb = r / NTOK, t = r % NTOK;
    float y0, y1, y2;
    if (t == 0) {
        y0 = cls[lane]       + pos[lane];
        y1 = cls[lane + 64]  + pos[lane + 64];
        y2 = cls[lane + 128] + pos[lane + 128];
    } else {
        const float* p = tok + ((size_t)bb * NPATCH + (t - 1)) * EMB;
        float x0 = p[lane], x1 = p[lane + 64], x2 = p[lane + 128];
        float s = x0 + x1 + x2;
#pragma unroll
        for (int off = 32; off; off >>= 1) s += __shfl_xor(s, off);
        const float mu = s * (1.f / 192.f);
        const float d0 = x0 - mu, d1 = x1 - mu, d2 = x2 - mu;
        float v = d0 * d0 + d1 * d1 + d2 * d2;
#pragma unroll
        for (int off = 32; off; off >>= 1) v += __shfl_xor(v, off);
        const float rstd = rsqrtf(v * (1.f / 192.f) + 1e-5f);
        const float* pr = pos + (size_t)t * EMB;
        y0 = d0 * rstd * w[lane]       + b[lane]       + pr[lane];
        y1 = d1 * rstd * w[lane + 64]  + b[lane + 64]  + pr[lane + 64];
        y2 = d2 * rstd * w[lane + 128] + b[lane + 128] + pr[lane + 128];
    }
    float* q = h + (size_t)r * EMB;
    q[lane] = y0; q[lane + 64] = y1; q[lane + 128] = y2;
    // norm1 LN (layer 0) -> bf16
    float s2 = y0 + y1 + y2;
#pragma unroll
    for (int off = 32; off; off >>= 1) s2 += __shfl_xor(s2, off);
    const float mu2 = s2 * (1.f / 192.f);
    const float e0 = y0 - mu2, e1 = y1 - mu2, e2 = y2 - mu2;
    float v2 = e0 * e0 + e1 * e1 + e2 * e2;
#pragma unroll
    for (int off = 32; off; off >>= 1) v2 += __shfl_xor(v2, off);
    const float rstd2 = rsqrtf(v2 * (1.f / 192.f) + 1e-5f);
    u16* o = outb + (size_t)r * EMB;
    o[lane]       = f2bf(e0 * rstd2 * n1w[lane]       + n1b[lane]);
    o[lane + 64]  = f2bf(e1 * rstd2 * n1w[lane + 64]  + n1b[lane + 64]);
    o[lane + 128] = f2bf(e2 * rstd2 * n1w[lane + 128] + n1b[lane + 128]);
}

// ---------------- LayerNorm over 192; bf16 or fp32 out ----------------
__global__ void ln192(const float* __restrict__ in, int in_stride,
                      const float* __restrict__ w, const float* __restrict__ b,
                      u16* __restrict__ outb, float* __restrict__ outf, int rows)
{
    const int wid = threadIdx.x >> 6, lane = threadIdx.x & 63;
    const int r = blockIdx.x * 4 + wid;
    if (r >= rows) return;
    const float* p = in + (size_t)r * in_stride;
    float x0 = p[lane], x1 = p[lane + 64], x2 = p[lane + 128];
    float s = x0 + x1 + x2;
#pragma unroll
    for (int off = 32; off; off >>= 1) s += __shfl_xor(s, off);
    const float mu = s * (1.f / 192.f);
    const float d0 = x0 - mu, d1 = x1 - mu, d2 = x2 - mu;
    float v = d0 * d0 + d1 * d1 + d2 * d2;
#pragma unroll
    for (int off = 32; off; off >>= 1) v += __shfl_xor(v, off);
    const float rstd = rsqrtf(v * (1.f / 192.f) + 1e-5f);
    const float y0 = d0 * rstd * w[lane]       + b[lane];
    const float y1 = d1 * rstd * w[lane + 64]  + b[lane + 64];
    const float y2 = d2 * rstd * w[lane + 128] + b[lane + 128];
    if (outf) {
        float* q = outf + (size_t)r * EMB;
        q[lane] = y0; q[lane + 64] = y1; q[lane + 128] = y2;
    } else {
        u16* q = outb + (size_t)r * EMB;
        q[lane] = f2bf(y0); q[lane + 64] = f2bf(y1); q[lane + 128] = f2bf(y2);
    }
}

// ---------------- MFMA classifier GEMM: C[64,N] = A[64,K] @ Bt[N,K]^T + bias ----
__global__ __launch_bounds__(256) void gemm_cls(
    const u16* __restrict__ A, const u16* __restrict__ Bt,
    const float* __restrict__ bias, float* __restrict__ C,
    int N, int K)
{
    __shared__ u16 As[64][72];
    __shared__ u16 Bs[64][72];
    const int tid = threadIdx.x;
    const int lane = tid & 63, wave = tid >> 6;
    const int wr = wave & 1, wc = wave >> 1;
    const int l16 = lane & 15, quad = lane >> 4;
    const int n0 = blockIdx.x * 64;
    const int srow = tid >> 2, skof = (tid & 3) * 16;

    floatx4 acc[2][2];
#pragma unroll
    for (int i = 0; i < 2; ++i)
#pragma unroll
        for (int j = 0; j < 2; ++j) acc[i][j] = (floatx4){0.f,0.f,0.f,0.f};

    const u16* ap = A + (size_t)srow * K + skof;
    int brow_g = n0 + srow;  if (brow_g > N - 1) brow_g = N - 1;
    const u16* bp = Bt + (size_t)brow_g * K + skof;

    for (int k0 = 0; k0 < K; k0 += 64) {
        const uint4 a0 = *(const uint4*)(ap + k0);
        const uint4 a1 = *(const uint4*)(ap + k0 + 8);
        const uint4 b0 = *(const uint4*)(bp + k0);
        const uint4 b1 = *(const uint4*)(bp + k0 + 8);
        if (k0) __syncthreads();
        *(uint4*)&As[srow][skof]     = a0;
        *(uint4*)&As[srow][skof + 8] = a1;
        *(uint4*)&Bs[srow][skof]     = b0;
        *(uint4*)&Bs[srow][skof + 8] = b1;
        __syncthreads();
#pragma unroll
        for (int ks = 0; ks < 2; ++ks) {
            short8 af[2], bf[2];
#pragma unroll
            for (int rf = 0; rf < 2; ++rf)
                af[rf] = *(const short8*)&As[wr*32 + rf*16 + l16][ks*32 + quad*8];
#pragma unroll
            for (int cf = 0; cf < 2; ++cf)
                bf[cf] = *(const short8*)&Bs[wc*32 + cf*16 + l16][ks*32 + quad*8];
#pragma unroll
            for (int rf = 0; rf < 2; ++rf)
#pragma unroll
                for (int cf = 0; cf < 2; ++cf)
                    acc[rf][cf] = __builtin_amdgcn_mfma_f32_16x16x32_bf16(af[rf], bf[cf], acc[rf][cf], 0, 0, 0);
        }
    }

#pragma unroll
    for (int rf = 0; rf < 2; ++rf) {
#pragma unroll
        for (int reg = 0; reg < 4; ++reg) {
            const int gm = wr*32 + rf*16 + quad*4 + reg;
#pragma unroll
            for (int cf = 0; cf < 2; ++cf) {
                const int gn = n0 + wc*32 + cf*16 + l16;
                if (gn < N)
                    C[(size_t)gm * N + gn] = acc[rf][cf][reg] + bias[gn];
            }
        }
    }
}

// ---------------- mean over tokens for exits (coalesced, bf16 out) ----------------
__global__ void pool_kernel(const float* __restrict__ h, u16* __restrict__ pooled)
{
    __shared__ float red[192];
    const int b = blockIdx.x;
    const int slice = threadIdx.x / 192;       // 0..1  (384 threads)
    const int e = threadIdx.x % 192;
    float s = 0.f;
    for (int n = slice; n < NTOK; n += 2)
        s += h[((size_t)(b * NTOK + n)) * EMB + e];
    if (slice == 1) red[e] = s;
    __syncthreads();
    if (slice == 0)
        pooled[b * EMB + e] = f2bf((s + red[e]) * (1.f / 197.f));
}

// ---------------- host launch ----------------
extern "C" void kernel_launch(void* const* d_in, const int* in_sizes, int n_in,
                              void* d_out, int out_size, void* d_ws, size_t ws_size,
                              hipStream_t stream)
{
    const float* x          = (const float*)d_in[0];
    const float* patch_w    = (const float*)d_in[1];
    const float* patch_b    = (const float*)d_in[2];
    const float* pe_norm_w  = (const float*)d_in[3];
    const float* pe_norm_b  = (const float*)d_in[4];
    const float* cls_token  = (const float*)d_in[5];
    const float* pos_embed  = (const float*)d_in[6];
    const float* norm1_w    = (const float*)d_in[7];
    const float* norm1_b    = (const float*)d_in[8];
    const float* qkv_w      = (const float*)d_in[9];
    const float* qkv_b      = (const float*)d_in[10];
    const float* proj_mat   = (const float*)d_in[11];
    const float* attn_pw    = (const float*)d_in[12];
    const float* attn_pb    = (const float*)d_in[13];
    const float* norm2_w    = (const float*)d_in[14];
    const float* norm2_b    = (const float*)d_in[15];
    const float* fc1_w      = (const float*)d_in[16];
    const float* fc1_b      = (const float*)d_in[17];
    const float* fc2_w      = (const float*)d_in[18];
    const float* fc2_b      = (const float*)d_in[19];
    const float* exit_w     = (const float*)d_in[20];
    const float* exit_b     = (const float*)d_in[21];
    const float* fnorm_w    = (const float*)d_in[22];
    const float* fnorm_b    = (const float*)d_in[23];
    const float* head_w     = (const float*)d_in[24];
    const float* head_b     = (const float*)d_in[25];
    float* out = (float*)d_out;

    float* ws = (float*)d_ws;
    float* H     = ws + 0;                  // 12608*192 fp32
    u16*   QKVB  = (u16*)(ws + 2420736);    // 12608*576 bf16
    u16*   XLNB  = (u16*)(ws + 6051840);    // 12608*192 bf16
    u16*   EXWT  = (u16*)(ws + 7262208);    // 3*1000*192 bf16 (288000 fl)
    u16*   HWT   = (u16*)(ws + 7550208);    // 1000*192 bf16 (96000 fl)
    u16*   POOLB = (u16*)(ws + 7646208);    // 64*192 bf16 (6144 fl)
    u16*   KVT   = (u16*)(ws + 19968000);   // 192*64*256 bf16
    u16*   MIDB  = (u16*)(ws + 21540864);   // 12608*768 bf16
    u16*   ATNB  = (u16*)(ws + 26382336);   // 12608*192 bf16
    float* KSUM  = ws + 27617280;           // 192*256
    u16*   QKVWT = (u16*)(ws + 27666432);   // 12*576*192 bf16
    u16*   APWT  = (u16*)(ws + 28329984);   // 12*192*192 bf16
    u16*   F1WT  = (u16*)(ws + 28551168);   // 12*768*192 bf16
    u16*   F2WT  = (u16*)(ws + 29435904);   // 12*192*768 bf16
    u16*   PATWB = (u16*)(ws + 30320640);   // 192*768 bf16
    u16*   PMB   = (u16*)(ws + 30394368);   // 12*256*64 bf16
    u16*   P_IMB = MIDB;                    // im2col alias (prologue only)
    float* TOK   = (float*)QKVB;            // patch tokens alias (prologue only)

    if (ws_size < (size_t)30492672 * sizeof(float)) return;

    // ---- weight prep ----
    cvt_bf16<<<(147456 + 255) / 256, 256, 0, stream>>>(patch_w, PATWB, 147456);
    cvt_bf16<<<(196608 + 255) / 256, 256, 0, stream>>>(proj_mat, PMB, 196608);
    tr_bf16_t<<<dim3(18, 6, 12), 256, 0, stream>>>(qkv_w,   QKVWT, 192, 576);
    tr_bf16_t<<<dim3(6, 6, 12),  256, 0, stream>>>(attn_pw, APWT,  192, 192);
    tr_bf16_t<<<dim3(24, 6, 12), 256, 0, stream>>>(fc1_w,   F1WT,  192, 768);
    tr_bf16_t<<<dim3(6, 24, 12), 256, 0, stream>>>(fc2_w,   F2WT,  768, 192);
    tr_bf16<<<(576000 + 255) / 256, 256, 0, stream>>>(exit_w, EXWT, 192, 1000, 576000);
    tr_bf16<<<(192000 + 255) / 256, 256, 0, stream>>>(head_w, HWT,  192, 1000, 192000);

    // ---- patch embed ----
    im2col_kernel<<<(MPAT * 768 + 255) / 256, 256, 0, stream>>>(x, P_IMB, MPAT * 768);
    gemm_bf16<<<294, 256, 0, stream>>>(P_IMB, PATWB, patch_b,
                                       TOK, nullptr, MPAT, EMB, 768, 0, 3);
    embed_finish<<<(MTOT + 3) / 4, 256, 0, stream>>>(TOK, cls_token, pos_embed,
                                                     pe_norm_w, pe_norm_b,
                                                     norm1_w, norm1_b, H, XLNB);

    // ---- transformer layers ----
    for (int i = 0; i < 12; ++i) {
        const u16* qwt  = QKVWT + (size_t)i * 576 * 192;
        const u16* pwt  = APWT  + (size_t)i * 192 * 192;
        const u16* f1wt = F1WT  + (size_t)i * 768 * 192;
        const u16* f2wt = F2WT  + (size_t)i * 192 * 768;
        const u16* pmb  = PMB   + (size_t)i * 256 * 64;
        const float* qb  = qkv_b   + (size_t)i * 576;
        const float* pb  = attn_pb + (size_t)i * 192;
        const float* f1b = fc1_b   + (size_t)i * 768;

        gemm_bf16<<<891, 256, 0, stream>>>(XLNB, qwt, qb,
                                           nullptr, QKVB, MTOT, 576, 192, 3, 9);
        attn_pkv<<<dim3(4, BHT), 256, 0, stream>>>(QKVB, pmb, KVT, KSUM);
        attn_out<<<dim3(4, BHT), 256, 0, stream>>>(QKVB, pmb, KVT, KSUM, ATNB);
        gemm_ln<<<394, 256, 0, stream>>>(ATNB, pwt, pb,
                                         norm2_w + (size_t)i * EMB, norm2_b + (size_t)i * EMB,
                                         H, XLNB, EMB);
        gemm_bf16<<<1188, 256, 0, stream>>>(XLNB, f1wt, f1b,
                                            nullptr, MIDB, MTOT, MLPD, 192, 2, 12);
        const float* nw = (i < 11) ? norm1_w + (size_t)(i + 1) * EMB : nullptr;
        const float* nb = (i < 11) ? norm1_b + (size_t)(i + 1) * EMB : nullptr;
        gemm_ln<<<394, 256, 0, stream>>>(MIDB, f2wt, fc2_b + (size_t)i * 192,
                                         nw, nb, H, XLNB, MLPD);

        const int e = (i == 3) ? 0 : (i == 7) ? 1 : (i == 11) ? 2 : -1;
        if (e >= 0) {
            pool_kernel<<<BB, 384, 0, stream>>>(H, POOLB);
            gemm_cls<<<16, 256, 0, stream>>>(POOLB, EXWT + (size_t)e * 1000 * 192,
                                             exit_b + (size_t)e * 1000,
                                             out + (size_t)(1 + e) * BB * NCLS,
                                             NCLS, EMB);
        }
    }

    // ---- head ----
    ln192<<<(BB + 3) / 4, 256, 0, stream>>>(H, NTOK * EMB, fnorm_w, fnorm_b,
                                            XLNB, nullptr, BB);
    gemm_cls<<<16, 256, 0, stream>>>(XLNB, HWT, head_b, out, NCLS, EMB);
}

// Round 6
// 1350.109 us; speedup vs baseline: 1.4139x; 1.0300x over previous
//
#include <hip/hip_runtime.h>
#include <math.h>

typedef unsigned short u16;
typedef unsigned int u32;
typedef __attribute__((ext_vector_type(8))) short short8;
typedef __attribute__((ext_vector_type(4))) float floatx4;

// ---------------- problem constants ----------------
#define BB 64
#define NTOK 197
#define NPATCH 196
#define EMB 192
#define NH 3
#define HD 64
#define FEAT 256
#define MLPD 768
#define NCLS 1000
#define MTOT (BB*NTOK)      // 12608
#define MPAT (BB*NPATCH)    // 12544
#define BHT (BB*NH)         // 192

// ---------------- bf16 helpers ----------------
__device__ __forceinline__ u16 f2bf(float x) {
    u32 u = __builtin_bit_cast(u32, x);
    u32 r = u + 0x7FFFu + ((u >> 16) & 1u);
    return (u16)(r >> 16);
}
__device__ __forceinline__ float bf2f(u16 u) {
    return __builtin_bit_cast(float, (u32)u << 16);
}
__device__ __forceinline__ float sqr8bf(uint4 v) {
    float s = 0.f;
    float t;
    t = bf2f((u16)(v.x & 0xffff)); s += t*t;  t = bf2f((u16)(v.x >> 16)); s += t*t;
    t = bf2f((u16)(v.y & 0xffff)); s += t*t;  t = bf2f((u16)(v.y >> 16)); s += t*t;
    t = bf2f((u16)(v.z & 0xffff)); s += t*t;  t = bf2f((u16)(v.z >> 16)); s += t*t;
    t = bf2f((u16)(v.w & 0xffff)); s += t*t;  t = bf2f((u16)(v.w >> 16)); s += t*t;
    return s;
}

// ---------------- weight prep ----------------
__global__ void cvt_bf16(const float* __restrict__ in, u16* __restrict__ out, int n)
{
    const int i = blockIdx.x * 256 + threadIdx.x;
    if (i < n) out[i] = f2bf(in[i]);
}

// in [L][R][C] fp32 -> out [L][C][R] bf16, coalesced via LDS 32x32 tiles (exact tiles)
__global__ void tr_bf16_t(const float* __restrict__ in, u16* __restrict__ out,
                          int R, int C)
{
    __shared__ u16 t[32][33];
    const int l = blockIdx.z;
    const int c0 = blockIdx.x * 32, r0 = blockIdx.y * 32;
    const int tx = threadIdx.x & 31, ty = threadIdx.x >> 5;   // ty 0..7
    const float* ip = in + ((size_t)l * R + r0) * C + c0;
#pragma unroll
    for (int j = 0; j < 4; ++j)
        t[ty + j*8][tx] = f2bf(ip[(size_t)(ty + j*8) * C + tx]);
    __syncthreads();
    u16* op = out + ((size_t)l * C + c0) * R + r0;
#pragma unroll
    for (int j = 0; j < 4; ++j)
        op[(size_t)(ty + j*8) * R + tx] = t[tx][ty + j*8];
}

// guarded variant (non-multiple-of-32 dims)
__global__ void tr_bf16_g(const float* __restrict__ in, u16* __restrict__ out,
                          int R, int C)
{
    __shared__ u16 t[32][33];
    const int l = blockIdx.z;
    const int c0 = blockIdx.x * 32, r0 = blockIdx.y * 32;
    const int tx = threadIdx.x & 31, ty = threadIdx.x >> 5;
    const float* ip = in + (size_t)l * R * C;
#pragma unroll
    for (int j = 0; j < 4; ++j) {
        const int r = r0 + ty + j*8, c = c0 + tx;
        t[ty + j*8][tx] = (r < R && c < C) ? f2bf(ip[(size_t)r * C + c]) : (u16)0;
    }
    __syncthreads();
    u16* op = out + (size_t)l * C * R;
#pragma unroll
    for (int j = 0; j < 4; ++j) {
        const int c = c0 + ty + j*8, r = r0 + tx;
        if (c < C && r < R)
            op[(size_t)c * R + r] = t[tx][ty + j*8];
    }
}

// ================= MFMA bf16 GEMM, 128x64 tile, XCD-swizzled =================
// C[M,N] = A[M,K] @ Bt[N,K]^T + bias.  Grid = 1D (mtiles*ntx) with bijective
// XCD-chunked swizzle.  mode 0: fp32 out ; mode 3: bf16 (swizzled-LDS store)
__global__ __launch_bounds__(256) void gemm_bf16(
    const u16* __restrict__ A, const u16* __restrict__ Bt,
    const float* __restrict__ bias,
    float* __restrict__ Cf, u16* __restrict__ Cb,
    int M, int N, int K, int mode, int ntx)
{
    __shared__ u16 As[128][72];
    __shared__ u16 Bs[64][72];
    const int tid = threadIdx.x;
    const int lane = tid & 63, wave = tid >> 6;
    const int l16 = lane & 15, quad = lane >> 4;
    const int nwg = gridDim.x;
    const int q = nwg >> 3, r = nwg & 7;
    const int xcd = blockIdx.x & 7, jj = blockIdx.x >> 3;
    const int wg = (xcd < r ? xcd * (q + 1) : r * (q + 1) + (xcd - r) * q) + jj;
    const int m0 = (wg / ntx) * 128, n0 = (wg % ntx) * 64;
    const int arow = tid >> 1, aof = (tid & 1) * 32;
    const int brow = tid >> 2, bof = (tid & 3) * 16;

    floatx4 acc[2][4];
#pragma unroll
    for (int i = 0; i < 2; ++i)
#pragma unroll
        for (int j = 0; j < 4; ++j) acc[i][j] = (floatx4){0.f,0.f,0.f,0.f};

    const int gmA = m0 + arow;
    const bool aok = (gmA < M);
    const u16* ap = A + (size_t)gmA * K + aof;
    const u16* bp = Bt + (size_t)(n0 + brow) * K + bof;

    for (int k0 = 0; k0 < K; k0 += 64) {
        uint4 a0 = {0,0,0,0}, a1 = {0,0,0,0}, a2 = {0,0,0,0}, a3 = {0,0,0,0};
        if (aok) {
            a0 = *(const uint4*)(ap + k0);
            a1 = *(const uint4*)(ap + k0 + 8);
            a2 = *(const uint4*)(ap + k0 + 16);
            a3 = *(const uint4*)(ap + k0 + 24);
        }
        const uint4 b0 = *(const uint4*)(bp + k0);
        const uint4 b1 = *(const uint4*)(bp + k0 + 8);
        if (k0) __syncthreads();
        *(uint4*)&As[arow][aof]      = a0;
        *(uint4*)&As[arow][aof + 8]  = a1;
        *(uint4*)&As[arow][aof + 16] = a2;
        *(uint4*)&As[arow][aof + 24] = a3;
        *(uint4*)&Bs[brow][bof]      = b0;
        *(uint4*)&Bs[brow][bof + 8]  = b1;
        __syncthreads();
#pragma unroll
        for (int ks = 0; ks < 2; ++ks) {
            short8 af[2], bf[4];
#pragma unroll
            for (int rf = 0; rf < 2; ++rf)
                af[rf] = *(const short8*)&As[wave*32 + rf*16 + l16][ks*32 + quad*8];
#pragma unroll
            for (int cf = 0; cf < 4; ++cf)
                bf[cf] = *(const short8*)&Bs[cf*16 + l16][ks*32 + quad*8];
#pragma unroll
            for (int rf = 0; rf < 2; ++rf)
#pragma unroll
                for (int cf = 0; cf < 4; ++cf)
                    acc[rf][cf] = __builtin_amdgcn_mfma_f32_16x16x32_bf16(af[rf], bf[cf], acc[rf][cf], 0, 0, 0);
        }
    }

    if (mode == 0) {
        const int rbase = m0 + wave * 32 + quad * 4;
        const int cbase = n0 + l16;
#pragma unroll
        for (int rf = 0; rf < 2; ++rf) {
#pragma unroll
            for (int reg = 0; reg < 4; ++reg) {
                const int gm = rbase + rf * 16 + reg;
                if (gm >= M) continue;
#pragma unroll
                for (int cf = 0; cf < 4; ++cf) {
                    const int gn = cbase + cf * 16;
                    Cf[(size_t)gm * N + gn] = acc[rf][cf][reg] + bias[gn];
                }
            }
        }
        return;
    }

    // bf16 epilogue: bias -> swizzled LDS tile -> coalesced uint4 stores
    __syncthreads();
#pragma unroll
    for (int rf = 0; rf < 2; ++rf) {
#pragma unroll
        for (int cf = 0; cf < 4; ++cf) {
            const int lc = cf * 16 + l16;
            const float bia = bias[n0 + lc];
#pragma unroll
            for (int reg = 0; reg < 4; ++reg) {
                const int lr = wave * 32 + rf * 16 + quad * 4 + reg;
                const float v = acc[rf][cf][reg] + bia;
                const int phys = (((lc >> 3) ^ (lr & 7)) << 3) | (lc & 7);
                As[lr][phys] = f2bf(v);
            }
        }
    }
    __syncthreads();
#pragma unroll
    for (int it = 0; it < 4; ++it) {
        const int idx = it * 256 + tid;
        const int row = idx >> 3, c8 = idx & 7;
        const int pc8 = c8 ^ (row & 7);
        const uint4 val = *(const uint4*)&As[row][pc8 * 8];
        const int gm = m0 + row;
        if (gm < M)
            *(uint4*)&Cb[(size_t)gm * N + n0 + c8 * 8] = val;
    }
}

// ================= fused GEMM(+bias+residual) + LayerNorm, 32-row tile ========
// Tile 32 x 192 (full row), M = 12608 = 394*32.  Used for attn-proj.
__global__ __launch_bounds__(256) void gemm_ln(
    const u16* __restrict__ A, const u16* __restrict__ Bt,
    const float* __restrict__ bias,
    const float* __restrict__ lnw, const float* __restrict__ lnb,
    float* __restrict__ H, u16* __restrict__ outb, int K)
{
    __shared__ u16 As[32][72];
    __shared__ u16 Bs[192][72];
    __shared__ float red_s[2][32][2];
    const int tid = threadIdx.x;
    const int lane = tid & 63, wave = tid >> 6;
    const int wr = wave & 1;          // row frag (16 rows)
    const int wc = wave >> 1;         // col half (96 cols)
    const int l16 = lane & 15, quad = lane >> 4;
    const int m0 = blockIdx.x * 32;
    const int srowA = tid >> 3, skofA = (tid & 7) * 8;
    const int srow = tid >> 2, skof = (tid & 3) * 16;

    floatx4 acc[6];
#pragma unroll
    for (int j = 0; j < 6; ++j) acc[j] = (floatx4){0.f,0.f,0.f,0.f};

    const u16* ap = A + (size_t)(m0 + srowA) * K + skofA;
    const u16* bp = Bt + (size_t)srow * K + skof;
    const size_t bstep = (size_t)64 * K;

    for (int k0 = 0; k0 < K; k0 += 64) {
        const uint4 a0 = *(const uint4*)(ap + k0);
        const uint4 b0 = *(const uint4*)(bp + k0);
        const uint4 b1 = *(const uint4*)(bp + k0 + 8);
        const uint4 b2 = *(const uint4*)(bp + bstep + k0);
        const uint4 b3 = *(const uint4*)(bp + bstep + k0 + 8);
        const uint4 b4 = *(const uint4*)(bp + 2*bstep + k0);
        const uint4 b5 = *(const uint4*)(bp + 2*bstep + k0 + 8);
        if (k0) __syncthreads();
        *(uint4*)&As[srowA][skofA]         = a0;
        *(uint4*)&Bs[srow][skof]           = b0;
        *(uint4*)&Bs[srow][skof + 8]       = b1;
        *(uint4*)&Bs[srow + 64][skof]      = b2;
        *(uint4*)&Bs[srow + 64][skof + 8]  = b3;
        *(uint4*)&Bs[srow + 128][skof]     = b4;
        *(uint4*)&Bs[srow + 128][skof + 8] = b5;
        __syncthreads();
#pragma unroll
        for (int ks = 0; ks < 2; ++ks) {
            const short8 af = *(const short8*)&As[wr*16 + l16][ks*32 + quad*8];
            short8 bf[6];
#pragma unroll
            for (int cf = 0; cf < 6; ++cf)
                bf[cf] = *(const short8*)&Bs[wc*96 + cf*16 + l16][ks*32 + quad*8];
#pragma unroll
            for (int cf = 0; cf < 6; ++cf)
                acc[cf] = __builtin_amdgcn_mfma_f32_16x16x32_bf16(af, bf[cf], acc[cf], 0, 0, 0);
        }
    }

    float s_[4], q_[4];
#pragma unroll
    for (int reg = 0; reg < 4; ++reg) { s_[reg] = 0.f; q_[reg] = 0.f; }

#pragma unroll
    for (int cf = 0; cf < 6; ++cf) {
        const int gn = wc * 96 + cf * 16 + l16;
        const float bia = bias[gn];
#pragma unroll
        for (int reg = 0; reg < 4; ++reg) {
            const int gm = m0 + wr * 16 + quad * 4 + reg;
            float v = acc[cf][reg] + bia + H[(size_t)gm * EMB + gn];
            H[(size_t)gm * EMB + gn] = v;
            acc[cf][reg] = v;
            s_[reg] += v;
            q_[reg] += v * v;
        }
    }

    if (lnw) {
#pragma unroll
        for (int reg = 0; reg < 4; ++reg) {
            float s = s_[reg], q = q_[reg];
            s += __shfl_xor(s, 1); q += __shfl_xor(q, 1);
            s += __shfl_xor(s, 2); q += __shfl_xor(q, 2);
            s += __shfl_xor(s, 4); q += __shfl_xor(q, 4);
            s += __shfl_xor(s, 8); q += __shfl_xor(q, 8);
            if (l16 == 0) {
                const int rl = wr * 16 + quad * 4 + reg;
                red_s[wc][rl][0] = s;
                red_s[wc][rl][1] = q;
            }
        }
        __syncthreads();
#pragma unroll
        for (int reg = 0; reg < 4; ++reg) {
            const int rl = wr * 16 + quad * 4 + reg;
            const float ts = red_s[0][rl][0] + red_s[1][rl][0];
            const float tq = red_s[0][rl][1] + red_s[1][rl][1];
            const float mu = ts * (1.f / 192.f);
            const float var = tq * (1.f / 192.f) - mu * mu;
            const float rstd = rsqrtf(fmaxf(var, 0.f) + 1e-5f);
            const int gm = m0 + rl;
#pragma unroll
            for (int cf = 0; cf < 6; ++cf) {
                const int gn = wc * 96 + cf * 16 + l16;
                const float y = (acc[cf][reg] - mu) * rstd * lnw[gn] + lnb[gn];
                outb[(size_t)gm * EMB + gn] = f2bf(y);
            }
        }
    }
}

// ================= fused MLP: fc1 + gelu + fc2 + residual + LN ================
// Tile 32 rows, grid 394.  H[r] += gelu(A@W1t^T + b1) @ W2t^T + b2 ;
// outb[r] = LN(H[r]) (bf16).  W1t [768][192], W2t [192][768].
// MLP chunked 64-wide: mid chunk computed, bf16-rounded into LDS, consumed
// immediately — identical arithmetic to the previous fc1(MIDB)+fc2 pair.
__global__ __launch_bounds__(256) void mlp_ln(
    const u16* __restrict__ A, const u16* __restrict__ W1t,
    const float* __restrict__ b1,
    const u16* __restrict__ W2t, const float* __restrict__ b2,
    const float* __restrict__ lnw, const float* __restrict__ lnb,
    float* __restrict__ H, u16* __restrict__ outb)
{
    __shared__ u16 As[32][200];
    __shared__ u16 W1s[64][200];
    __shared__ u16 W2s[192][72];
    __shared__ u16 Ms[32][72];
    __shared__ float red_s[4][32][2];
    const int tid = threadIdx.x;
    const int lane = tid & 63, wave = tid >> 6;
    const int l16 = lane & 15, quad = lane >> 4;
    const int m0 = blockIdx.x * 32;

    // stage A tile (32 x 192)
    {
        const int row = tid >> 3, cb = (tid & 7) * 24;
        const u16* ap = A + (size_t)(m0 + row) * EMB + cb;
#pragma unroll
        for (int j = 0; j < 3; ++j)
            *(uint4*)&As[row][cb + j * 8] = *(const uint4*)(ap + j * 8);
    }
    __syncthreads();
    // A fragments in registers (reused across all 12 chunks)
    short8 af[2][6];
#pragma unroll
    for (int rf = 0; rf < 2; ++rf)
#pragma unroll
        for (int ks = 0; ks < 6; ++ks)
            af[rf][ks] = *(const short8*)&As[rf*16 + l16][ks*32 + quad*8];

    floatx4 acc[2][3];
#pragma unroll
    for (int i = 0; i < 2; ++i)
#pragma unroll
        for (int j = 0; j < 3; ++j) acc[i][j] = (floatx4){0.f,0.f,0.f,0.f};

    for (int c = 0; c < 12; ++c) {
        if (c) __syncthreads();               // prev chunk's W2s/Ms reads done
        // stage W1 chunk rows [c*64 .. +63][192]
        {
            const int row = tid >> 2, cb = (tid & 3) * 48;
            const u16* wp = W1t + (size_t)(c * 64 + row) * EMB + cb;
#pragma unroll
            for (int j = 0; j < 6; ++j)
                *(uint4*)&W1s[row][cb + j * 8] = *(const uint4*)(wp + j * 8);
        }
        // stage W2 chunk cols [c*64 .. +63] for all 192 rows
#pragma unroll
        for (int j = 0; j < 6; ++j) {
            const int idx = j * 256 + tid;
            const int e = idx >> 3, o = (idx & 7) * 8;
            *(uint4*)&W2s[e][o] = *(const uint4*)(W2t + (size_t)e * MLPD + c * 64 + o);
        }
        __syncthreads();

        // mid chunk: C[n 32][f 16-per-wave], K = 192
        floatx4 mf[2] = {(floatx4){0.f,0.f,0.f,0.f}, (floatx4){0.f,0.f,0.f,0.f}};
#pragma unroll
        for (int ks = 0; ks < 6; ++ks) {
            const short8 w1f = *(const short8*)&W1s[wave*16 + l16][ks*32 + quad*8];
            mf[0] = __builtin_amdgcn_mfma_f32_16x16x32_bf16(af[0][ks], w1f, mf[0], 0, 0, 0);
            mf[1] = __builtin_amdgcn_mfma_f32_16x16x32_bf16(af[1][ks], w1f, mf[1], 0, 0, 0);
        }
        // gelu + bf16 round -> Ms[n][f_loc]
        const float bia = b1[c * 64 + wave * 16 + l16];
#pragma unroll
        for (int rf = 0; rf < 2; ++rf)
#pragma unroll
            for (int reg = 0; reg < 4; ++reg) {
                float v = mf[rf][reg] + bia;
                v = 0.5f * v * (1.f + erff(v * 0.70710678118654752f));
                Ms[rf*16 + quad*4 + reg][wave*16 + l16] = f2bf(v);
            }
        __syncthreads();

        // out accumulate: C[n 32][e 48-per-wave], K = 64
#pragma unroll
        for (int ks2 = 0; ks2 < 2; ++ks2) {
            short8 a2[2], w2f[3];
#pragma unroll
            for (int rf = 0; rf < 2; ++rf)
                a2[rf] = *(const short8*)&Ms[rf*16 + l16][ks2*32 + quad*8];
#pragma unroll
            for (int cf = 0; cf < 3; ++cf)
                w2f[cf] = *(const short8*)&W2s[wave*48 + cf*16 + l16][ks2*32 + quad*8];
#pragma unroll
            for (int rf = 0; rf < 2; ++rf)
#pragma unroll
                for (int cf = 0; cf < 3; ++cf)
                    acc[rf][cf] = __builtin_amdgcn_mfma_f32_16x16x32_bf16(a2[rf], w2f[cf], acc[rf][cf], 0, 0, 0);
        }
    }

    // epilogue: bias + residual -> H (fp32), row sum/sumsq
    float s_[2][4], q_[2][4];
#pragma unroll
    for (int rf = 0; rf < 2; ++rf)
#pragma unroll
        for (int reg = 0; reg < 4; ++reg) { s_[rf][reg] = 0.f; q_[rf][reg] = 0.f; }

#pragma unroll
    for (int rf = 0; rf < 2; ++rf) {
#pragma unroll
        for (int cf = 0; cf < 3; ++cf) {
            const int gn = wave * 48 + cf * 16 + l16;
            const float bia = b2[gn];
#pragma unroll
            for (int reg = 0; reg < 4; ++reg) {
                const int gm = m0 + rf * 16 + quad * 4 + reg;
                float v = acc[rf][cf][reg] + bia + H[(size_t)gm * EMB + gn];
                H[(size_t)gm * EMB + gn] = v;
                acc[rf][cf][reg] = v;
                s_[rf][reg] += v;
                q_[rf][reg] += v * v;
            }
        }
    }

    if (lnw) {
#pragma unroll
        for (int rf = 0; rf < 2; ++rf)
#pragma unroll
            for (int reg = 0; reg < 4; ++reg) {
                float s = s_[rf][reg], q = q_[rf][reg];
                s += __shfl_xor(s, 1); q += __shfl_xor(q, 1);
                s += __shfl_xor(s, 2); q += __shfl_xor(q, 2);
                s += __shfl_xor(s, 4); q += __shfl_xor(q, 4);
                s += __shfl_xor(s, 8); q += __shfl_xor(q, 8);
                if (l16 == 0) {
                    const int rl = rf * 16 + quad * 4 + reg;
                    red_s[wave][rl][0] = s;
                    red_s[wave][rl][1] = q;
                }
            }
        __syncthreads();
#pragma unroll
        for (int rf = 0; rf < 2; ++rf) {
#pragma unroll
            for (int reg = 0; reg < 4; ++reg) {
                const int rl = rf * 16 + quad * 4 + reg;
                const float ts = red_s[0][rl][0] + red_s[1][rl][0]
                               + red_s[2][rl][0] + red_s[3][rl][0];
                const float tq = red_s[0][rl][1] + red_s[1][rl][1]
                               + red_s[2][rl][1] + red_s[3][rl][1];
                const float mu = ts * (1.f / 192.f);
                const float var = tq * (1.f / 192.f) - mu * mu;
                const float rstd = rsqrtf(fmaxf(var, 0.f) + 1e-5f);
                const int gm = m0 + rl;
#pragma unroll
                for (int cf = 0; cf < 3; ++cf) {
                    const int gn = wave * 48 + cf * 16 + l16;
                    const float y = (acc[rf][cf][reg] - mu) * rstd * lnw[gn] + lnb[gn];
                    outb[(size_t)gm * EMB + gn] = f2bf(y);
                }
            }
        }
    }
}

// ================= fused performer attention, stage 1 (f-split) ==============
__global__ __launch_bounds__(256) void attn_pkv(
    const u16* __restrict__ qkv, const u16* __restrict__ pmb,
    u16* __restrict__ kvT, float* __restrict__ ksum)
{
    __shared__ u16 pm_s[64][72];      // [f_loc][d]
    __shared__ u16 kt_s[64][72];      // [n][d] tile
    __shared__ u16 vT_s[64][72];      // [d][n] tile
    __shared__ u16 pkT_s[64][72];     // [f_loc][n] tile
    __shared__ float nrm_s[64];
    __shared__ float ksum_s[64];

    const int tid = threadIdx.x;
    const int lane = tid & 63, wave = tid >> 6;
    const int l16 = lane & 15, quad = lane >> 4;
    const int fq = blockIdx.x, bh = blockIdx.y, b = bh / NH, h = bh % NH;
    const int fwave = wave * 16;
    const int srow = tid >> 2, skof = (tid & 3) * 16;
    const float scale = 0.35355339059327373f;

#pragma unroll
    for (int j = 0; j < 2; ++j) {
        const int flat = j * 256 + tid;
        const int row = flat >> 3, o = (flat & 7) * 8;
        *(uint4*)&pm_s[row][o] = *(const uint4*)(pmb + (size_t)(fq * 64 + row) * 64 + o);
    }
    if (tid < 64) ksum_s[tid] = 0.f;

    floatx4 kv[4];
#pragma unroll
    for (int i = 0; i < 4; ++i) kv[i] = (floatx4){0.f,0.f,0.f,0.f};

    uint4 k0v = {0,0,0,0}, k1v = {0,0,0,0}, v0v = {0,0,0,0}, v1v = {0,0,0,0};
    {
        const u16* kp = qkv + ((size_t)(b * NTOK + srow)) * 576 + 192 + h * 64 + skof;
        k0v = *(const uint4*)kp; k1v = *(const uint4*)(kp + 8);
        v0v = *(const uint4*)(kp + 192); v1v = *(const uint4*)(kp + 200);
    }

    for (int t = 0; t < 4; ++t) {
        const int ncur = t * 64 + srow;
        if (t) __syncthreads();
        *(uint4*)&kt_s[srow][skof]     = k0v;
        *(uint4*)&kt_s[srow][skof + 8] = k1v;
        {
            u16 vv[16];
            vv[0]=(u16)(v0v.x&0xffff);  vv[1]=(u16)(v0v.x>>16);
            vv[2]=(u16)(v0v.y&0xffff);  vv[3]=(u16)(v0v.y>>16);
            vv[4]=(u16)(v0v.z&0xffff);  vv[5]=(u16)(v0v.z>>16);
            vv[6]=(u16)(v0v.w&0xffff);  vv[7]=(u16)(v0v.w>>16);
            vv[8]=(u16)(v1v.x&0xffff);  vv[9]=(u16)(v1v.x>>16);
            vv[10]=(u16)(v1v.y&0xffff); vv[11]=(u16)(v1v.y>>16);
            vv[12]=(u16)(v1v.z&0xffff); vv[13]=(u16)(v1v.z>>16);
            vv[14]=(u16)(v1v.w&0xffff); vv[15]=(u16)(v1v.w>>16);
#pragma unroll
            for (int j = 0; j < 16; ++j) vT_s[skof + j][srow] = vv[j];
        }
        float sq = sqr8bf(k0v) + sqr8bf(k1v);
        sq += __shfl_xor(sq, 1);
        sq += __shfl_xor(sq, 2);
        if ((tid & 3) == 0) nrm_s[srow] = (ncur < NTOK) ? 0.5f * sq : 1e30f;
        __syncthreads();

        if (t < 3) {
            const int n = (t + 1) * 64 + srow;
            k0v = (uint4){0,0,0,0}; k1v = (uint4){0,0,0,0};
            v0v = (uint4){0,0,0,0}; v1v = (uint4){0,0,0,0};
            if (n < NTOK) {
                const u16* kp = qkv + ((size_t)(b * NTOK + n)) * 576 + 192 + h * 64 + skof;
                k0v = *(const uint4*)kp; k1v = *(const uint4*)(kp + 8);
                v0v = *(const uint4*)(kp + 192); v1v = *(const uint4*)(kp + 200);
            }
        }

        floatx4 pa[4];
#pragma unroll
        for (int i = 0; i < 4; ++i) pa[i] = (floatx4){0.f,0.f,0.f,0.f};
#pragma unroll
        for (int ks = 0; ks < 2; ++ks) {
            const short8 bpm = *(const short8*)&pm_s[fwave + l16][ks*32 + quad*8];
#pragma unroll
            for (int rf = 0; rf < 4; ++rf) {
                const short8 a = *(const short8*)&kt_s[rf*16 + l16][ks*32 + quad*8];
                pa[rf] = __builtin_amdgcn_mfma_f32_16x16x32_bf16(a, bpm, pa[rf], 0, 0, 0);
            }
        }

        float ksp = 0.f;
        const int floc = fwave + l16;
#pragma unroll
        for (int rf = 0; rf < 4; ++rf) {
            const int nl = rf * 16 + quad * 4;
            const u16 b0 = f2bf(__expf(pa[rf][0] - nrm_s[nl + 0]) * scale);
            const u16 b1 = f2bf(__expf(pa[rf][1] - nrm_s[nl + 1]) * scale);
            const u16 b2 = f2bf(__expf(pa[rf][2] - nrm_s[nl + 2]) * scale);
            const u16 b3 = f2bf(__expf(pa[rf][3] - nrm_s[nl + 3]) * scale);
            ksp += bf2f(b0) + bf2f(b1) + bf2f(b2) + bf2f(b3);
            *(u32*)&pkT_s[floc][nl]     = (u32)b0 | ((u32)b1 << 16);
            *(u32*)&pkT_s[floc][nl + 2] = (u32)b2 | ((u32)b3 << 16);
        }
        {
            float v = ksp;
            v += __shfl_xor(v, 16);
            v += __shfl_xor(v, 32);
            if (quad == 0) ksum_s[floc] += v;
        }

#pragma unroll
        for (int ks = 0; ks < 2; ++ks) {
            const short8 bpk = *(const short8*)&pkT_s[fwave + l16][ks*32 + quad*8];
#pragma unroll
            for (int rf = 0; rf < 4; ++rf) {
                const short8 a = *(const short8*)&vT_s[rf*16 + l16][ks*32 + quad*8];
                kv[rf] = __builtin_amdgcn_mfma_f32_16x16x32_bf16(a, bpk, kv[rf], 0, 0, 0);
            }
        }
    }

    __syncthreads();
    if (tid < 64) ksum[(size_t)bh * 256 + fq * 64 + tid] = ksum_s[tid];
    const int fg = fq * 64 + fwave + l16;
#pragma unroll
    for (int rf = 0; rf < 4; ++rf) {
#pragma unroll
        for (int reg = 0; reg < 4; ++reg) {
            const int d = rf * 16 + quad * 4 + reg;
            kvT[((size_t)bh * 64 + d) * 256 + fg] = f2bf(kv[rf][reg]);
        }
    }
}

// ================= fused performer attention, stage 2 =====================
__global__ __launch_bounds__(256) void attn_out(
    const u16* __restrict__ qkv, const u16* __restrict__ pmb,
    const u16* __restrict__ kvT, const float* __restrict__ ksum,
    u16* __restrict__ attn_o)
{
    __shared__ u16 pm_s[256][72];
    __shared__ u16 q_s[64][72];
    __shared__ u16 pq_s[64][264];
    __shared__ u16 kv_s[64][264];
    __shared__ float nrm_s[64];
    __shared__ float den_s[4][64];

    const int tid = threadIdx.x;
    const int lane = tid & 63, wave = tid >> 6;
    const int l16 = lane & 15, quad = lane >> 4;
    const int bh = blockIdx.y, b = bh / NH, h = bh % NH;
    const int n0 = blockIdx.x * 64;
    const int fbase = wave * 64;
    const int srow = tid >> 2, skof = (tid & 3) * 16;
    const float scale = 0.35355339059327373f;

#pragma unroll
    for (int j = 0; j < 8; ++j) {
        const int flat = j * 256 + tid;
        const int f = flat >> 3, o = (flat & 7) * 8;
        *(uint4*)&pm_s[f][o] = *(const uint4*)(pmb + f * 64 + o);
    }
#pragma unroll
    for (int j = 0; j < 8; ++j) {
        const int flat = j * 256 + tid;
        const int d = flat >> 5, o = (flat & 31) * 8;
        *(uint4*)&kv_s[d][o] = *(const uint4*)(kvT + ((size_t)bh * 64 + d) * 256 + o);
    }
    {
        const int n = n0 + srow;
        uint4 q0 = {0,0,0,0}, q1 = {0,0,0,0};
        if (n < NTOK) {
            const u16* qp = qkv + ((size_t)(b * NTOK + n)) * 576 + h * 64 + skof;
            q0 = *(const uint4*)qp; q1 = *(const uint4*)(qp + 8);
        }
        *(uint4*)&q_s[srow][skof]     = q0;
        *(uint4*)&q_s[srow][skof + 8] = q1;
        float sq = sqr8bf(q0) + sqr8bf(q1);
        sq += __shfl_xor(sq, 1);
        sq += __shfl_xor(sq, 2);
        if ((tid & 3) == 0) nrm_s[srow] = (n < NTOK) ? 0.5f * sq : 1e30f;
    }
    float ksr[4];
#pragma unroll
    for (int cf = 0; cf < 4; ++cf)
        ksr[cf] = ksum[(size_t)bh * 256 + fbase + cf * 16 + l16];
    __syncthreads();

    floatx4 pa[4][4];
#pragma unroll
    for (int i = 0; i < 4; ++i)
#pragma unroll
        for (int j = 0; j < 4; ++j) pa[i][j] = (floatx4){0.f,0.f,0.f,0.f};
#pragma unroll
    for (int ks = 0; ks < 2; ++ks) {
        short8 a[4], bb[4];
#pragma unroll
        for (int rf = 0; rf < 4; ++rf)
            a[rf] = *(const short8*)&q_s[rf*16 + l16][ks*32 + quad*8];
#pragma unroll
        for (int cf = 0; cf < 4; ++cf)
            bb[cf] = *(const short8*)&pm_s[fbase + cf*16 + l16][ks*32 + quad*8];
#pragma unroll
        for (int rf = 0; rf < 4; ++rf)
#pragma unroll
            for (int cf = 0; cf < 4; ++cf)
                pa[rf][cf] = __builtin_amdgcn_mfma_f32_16x16x32_bf16(a[rf], bb[cf], pa[rf][cf], 0, 0, 0);
    }

    float dpart[16];
#pragma unroll
    for (int i = 0; i < 16; ++i) dpart[i] = 0.f;
#pragma unroll
    for (int rf = 0; rf < 4; ++rf) {
        const int nl = rf * 16 + quad * 4;
        const float nr0 = nrm_s[nl + 0], nr1 = nrm_s[nl + 1];
        const float nr2 = nrm_s[nl + 2], nr3 = nrm_s[nl + 3];
#pragma unroll
        for (int cf = 0; cf < 4; ++cf) {
            const int f = fbase + cf * 16 + l16;
            const u16 b0 = f2bf(__expf(pa[rf][cf][0] - nr0) * scale);
            const u16 b1 = f2bf(__expf(pa[rf][cf][1] - nr1) * scale);
            const u16 b2 = f2bf(__expf(pa[rf][cf][2] - nr2) * scale);
            const u16 b3 = f2bf(__expf(pa[rf][cf][3] - nr3) * scale);
            pq_s[nl + 0][f] = b0;
            pq_s[nl + 1][f] = b1;
            pq_s[nl + 2][f] = b2;
            pq_s[nl + 3][f] = b3;
            dpart[rf*4 + 0] += bf2f(b0) * ksr[cf];
            dpart[rf*4 + 1] += bf2f(b1) * ksr[cf];
            dpart[rf*4 + 2] += bf2f(b2) * ksr[cf];
            dpart[rf*4 + 3] += bf2f(b3) * ksr[cf];
        }
    }
#pragma unroll
    for (int i = 0; i < 16; ++i) {
        float d = dpart[i];
        d += __shfl_xor(d, 1); d += __shfl_xor(d, 2);
        d += __shfl_xor(d, 4); d += __shfl_xor(d, 8);
        dpart[i] = d;
    }
    if (l16 == 0) {
#pragma unroll
        for (int rf = 0; rf < 4; ++rf)
#pragma unroll
            for (int reg = 0; reg < 4; ++reg)
                den_s[wave][rf*16 + quad*4 + reg] = dpart[rf*4 + reg];
    }
    __syncthreads();

    const int wr = wave & 1, wc = wave >> 1;
    floatx4 oc[2][2];
#pragma unroll
    for (int i = 0; i < 2; ++i)
#pragma unroll
        for (int j = 0; j < 2; ++j) oc[i][j] = (floatx4){0.f,0.f,0.f,0.f};
#pragma unroll
    for (int ks = 0; ks < 8; ++ks) {
        short8 a[2], bb[2];
#pragma unroll
        for (int rf = 0; rf < 2; ++rf)
            a[rf] = *(const short8*)&pq_s[wr*32 + rf*16 + l16][ks*32 + quad*8];
#pragma unroll
        for (int cf = 0; cf < 2; ++cf)
            bb[cf] = *(const short8*)&kv_s[wc*32 + cf*16 + l16][ks*32 + quad*8];
#pragma unroll
        for (int rf = 0; rf < 2; ++rf)
#pragma unroll
            for (int cf = 0; cf < 2; ++cf)
                oc[rf][cf] = __builtin_amdgcn_mfma_f32_16x16x32_bf16(a[rf], bb[cf], oc[rf][cf], 0, 0, 0);
    }

#pragma unroll
    for (int rf = 0; rf < 2; ++rf) {
#pragma unroll
        for (int reg = 0; reg < 4; ++reg) {
            const int nl = wr*32 + rf*16 + quad*4 + reg;
            const int gn = n0 + nl;
            if (gn >= NTOK) continue;
            const float di = 1.f / (den_s[0][nl] + den_s[1][nl] + den_s[2][nl] + den_s[3][nl]);
#pragma unroll
            for (int cf = 0; cf < 2; ++cf) {
                const int d = wc*32 + cf*16 + l16;
                attn_o[((size_t)(b * NTOK + gn)) * EMB + h * 64 + d] =
                    f2bf(oc[rf][cf][reg] * di);
            }
        }
    }
}

// ---------------- im2col (bf16 out) ----------------
__global__ void im2col_kernel(const float* __restrict__ x, u16* __restrict__ p, int total)
{
    const int i = blockIdx.x * 256 + threadIdx.x;
    if (i >= total) return;
    const int col = i % 768, row = i / 768;
    const int px = col & 15, py = (col >> 4) & 15, c = col >> 8;
    const int gx = row % 14, gy = (row / 14) % 14, b = row / 196;
    p[i] = f2bf(x[((size_t)(b * 3 + c) * 224 + gy * 16 + py) * 224 + gx * 16 + px]);
}

// ---------------- patch-embed finish + fused norm1 LN of layer 0 ----------------
__global__ void embed_finish(const float* __restrict__ tok, const float* __restrict__ cls,
                             const float* __restrict__ pos, const float* __restrict__ w,
                             const float* __restrict__ b,
                             const float* __restrict__ n1w, const float* __restrict__ n1b,
                             float* __restrict__ h, u16* __restrict__ outb)
{
    const int wid = threadIdx.x >> 6, lane = threadIdx.x & 63;
    const int r = blockIdx.x * 4 + wid;
    if (r >= MTOT) return;
    const int bb = r / NTOK, t = r % NTOK;
    float y0, y1, y2;
    if (t == 0) {
        y0 = cls[lane]       + pos[lane];
        y1 = cls[lane + 64]  + pos[lane + 64];
        y2 = cls[lane + 128] + pos[lane + 128];
    } else {
        const float* p = tok + ((size_t)bb * NPATCH + (t - 1)) * EMB;
        float x0 = p[lane], x1 = p[lane + 64], x2 = p[lane + 128];
        float s = x0 + x1 + x2;
#pragma unroll
        for (int off = 32; off; off >>= 1) s += __shfl_xor(s, off);
        const float mu = s * (1.f / 192.f);
        const float d0 = x0 - mu, d1 = x1 - mu, d2 = x2 - mu;
        float v = d0 * d0 + d1 * d1 + d2 * d2;
#pragma unroll
        for (int off = 32; off; off >>= 1) v += __shfl_xor(v, off);
        const float rstd = rsqrtf(v * (1.f / 192.f) + 1e-5f);
        const float* pr = pos + (size_t)t * EMB;
        y0 = d0 * rstd * w[lane]       + b[lane]       + pr[lane];
        y1 = d1 * rstd * w[lane + 64]  + b[lane + 64]  + pr[lane + 64];
        y2 = d2 * rstd * w[lane + 128] + b[lane + 128] + pr[lane + 128];
    }
    float* q = h + (size_t)r * EMB;
    q[lane] = y0; q[lane + 64] = y1; q[lane + 128] = y2;
    float s2 = y0 + y1 + y2;
#pragma unroll
    for (int off = 32; off; off >>= 1) s2 += __shfl_xor(s2, off);
    const float mu2 = s2 * (1.f / 192.f);
    const float e0 = y0 - mu2, e1 = y1 - mu2, e2 = y2 - mu2;
    float v2 = e0 * e0 + e1 * e1 + e2 * e2;
#pragma unroll
    for (int off = 32; off; off >>= 1) v2 += __shfl_xor(v2, off);
    const float rstd2 = rsqrtf(v2 * (1.f / 192.f) + 1e-5f);
    u16* o = outb + (size_t)r * EMB;
    o[lane]       = f2bf(e0 * rstd2 * n1w[lane]       + n1b[lane]);
    o[lane + 64]  = f2bf(e1 * rstd2 * n1w[lane + 64]  + n1b[lane + 64]);
    o[lane + 128] = f2bf(e2 * rstd2 * n1w[lane + 128] + n1b[lane + 128]);
}

// ---------------- LayerNorm over 192; bf16 or fp32 out ----------------
__global__ void ln192(const float* __restrict__ in, int in_stride,
                      const float* __restrict__ w, const float* __restrict__ b,
                      u16* __restrict__ outb, float* __restrict__ outf, int rows)
{
    const int wid = threadIdx.x >> 6, lane = threadIdx.x & 63;
    const int r = blockIdx.x * 4 + wid;
    if (r >= rows) return;
    const float* p = in + (size_t)r * in_stride;
    float x0 = p[lane], x1 = p[lane + 64], x2 = p[lane + 128];
    float s = x0 + x1 + x2;
#pragma unroll
    for (int off = 32; off; off >>= 1) s += __shfl_xor(s, off);
    const float mu = s * (1.f / 192.f);
    const float d0 = x0 - mu, d1 = x1 - mu, d2 = x2 - mu;
    float v = d0 * d0 + d1 * d1 + d2 * d2;
#pragma unroll
    for (int off = 32; off; off >>= 1) v += __shfl_xor(v, off);
    const float rstd = rsqrtf(v * (1.f / 192.f) + 1e-5f);
    const float y0 = d0 * rstd * w[lane]       + b[lane];
    const float y1 = d1 * rstd * w[lane + 64]  + b[lane + 64];
    const float y2 = d2 * rstd * w[lane + 128] + b[lane + 128];
    if (outf) {
        float* q = outf + (size_t)r * EMB;
        q[lane] = y0; q[lane + 64] = y1; q[lane + 128] = y2;
    } else {
        u16* q = outb + (size_t)r * EMB;
        q[lane] = f2bf(y0); q[lane + 64] = f2bf(y1); q[lane + 128] = f2bf(y2);
    }
}

// ---------------- MFMA classifier GEMM: C[64,N] = A[64,K] @ Bt[N,K]^T + bias ----
__global__ __launch_bounds__(256) void gemm_cls(
    const u16* __restrict__ A, const u16* __restrict__ Bt,
    const float* __restrict__ bias, float* __restrict__ C,
    int N, int K)
{
    __shared__ u16 As[64][72];
    __shared__ u16 Bs[64][72];
    const int tid = threadIdx.x;
    const int lane = tid & 63, wave = tid >> 6;
    const int wr = wave & 1, wc = wave >> 1;
    const int l16 = lane & 15, quad = lane >> 4;
    const int n0 = blockIdx.x * 64;
    const int srow = tid >> 2, skof = (tid & 3) * 16;

    floatx4 acc[2][2];
#pragma unroll
    for (int i = 0; i < 2; ++i)
#pragma unroll
        for (int j = 0; j < 2; ++j) acc[i][j] = (floatx4){0.f,0.f,0.f,0.f};

    const u16* ap = A + (size_t)srow * K + skof;
    int brow_g = n0 + srow;  if (brow_g > N - 1) brow_g = N - 1;
    const u16* bp = Bt + (size_t)brow_g * K + skof;

    for (int k0 = 0; k0 < K; k0 += 64) {
        const uint4 a0 = *(const uint4*)(ap + k0);
        const uint4 a1 = *(const uint4*)(ap + k0 + 8);
        const uint4 b0 = *(const uint4*)(bp + k0);
        const uint4 b1 = *(const uint4*)(bp + k0 + 8);
        if (k0) __syncthreads();
        *(uint4*)&As[srow][skof]     = a0;
        *(uint4*)&As[srow][skof + 8] = a1;
        *(uint4*)&Bs[srow][skof]     = b0;
        *(uint4*)&Bs[srow][skof + 8] = b1;
        __syncthreads();
#pragma unroll
        for (int ks = 0; ks < 2; ++ks) {
            short8 af[2], bf[2];
#pragma unroll
            for (int rf = 0; rf < 2; ++rf)
                af[rf] = *(const short8*)&As[wr*32 + rf*16 + l16][ks*32 + quad*8];
#pragma unroll
            for (int cf = 0; cf < 2; ++cf)
                bf[cf] = *(const short8*)&Bs[wc*32 + cf*16 + l16][ks*32 + quad*8];
#pragma unroll
            for (int rf = 0; rf < 2; ++rf)
#pragma unroll
                for (int cf = 0; cf < 2; ++cf)
                    acc[rf][cf] = __builtin_amdgcn_mfma_f32_16x16x32_bf16(af[rf], bf[cf], acc[rf][cf], 0, 0, 0);
        }
    }

#pragma unroll
    for (int rf = 0; rf < 2; ++rf) {
#pragma unroll
        for (int reg = 0; reg < 4; ++reg) {
            const int gm = wr*32 + rf*16 + quad*4 + reg;
#pragma unroll
            for (int cf = 0; cf < 2; ++cf) {
                const int gn = n0 + wc*32 + cf*16 + l16;
                if (gn < N)
                    C[(size_t)gm * N + gn] = acc[rf][cf][reg] + bias[gn];
            }
        }
    }
}

// ---------------- mean over tokens for exits (coalesced, bf16 out) ----------------
__global__ void pool_kernel(const float* __restrict__ h, u16* __restrict__ pooled)
{
    __shared__ float red[192];
    const int b = blockIdx.x;
    const int slice = threadIdx.x / 192;       // 0..1  (384 threads)
    const int e = threadIdx.x % 192;
    float s = 0.f;
    for (int n = slice; n < NTOK; n += 2)
        s += h[((size_t)(b * NTOK + n)) * EMB + e];
    if (slice == 1) red[e] = s;
    __syncthreads();
    if (slice == 0)
        pooled[b * EMB + e] = f2bf((s + red[e]) * (1.f / 197.f));
}

// ---------------- host launch ----------------
extern "C" void kernel_launch(void* const* d_in, const int* in_sizes, int n_in,
                              void* d_out, int out_size, void* d_ws, size_t ws_size,
                              hipStream_t stream)
{
    const float* x          = (const float*)d_in[0];
    const float* patch_w    = (const float*)d_in[1];
    const float* patch_b    = (const float*)d_in[2];
    const float* pe_norm_w  = (const float*)d_in[3];
    const float* pe_norm_b  = (const float*)d_in[4];
    const float* cls_token  = (const float*)d_in[5];
    const float* pos_embed  = (const float*)d_in[6];
    const float* norm1_w    = (const float*)d_in[7];
    const float* norm1_b    = (const float*)d_in[8];
    const float* qkv_w      = (const float*)d_in[9];
    const float* qkv_b      = (const float*)d_in[10];
    const float* proj_mat   = (const float*)d_in[11];
    const float* attn_pw    = (const float*)d_in[12];
    const float* attn_pb    = (const float*)d_in[13];
    const float* norm2_w    = (const float*)d_in[14];
    const float* norm2_b    = (const float*)d_in[15];
    const float* fc1_w      = (const float*)d_in[16];
    const float* fc1_b      = (const float*)d_in[17];
    const float* fc2_w      = (const float*)d_in[18];
    const float* fc2_b      = (const float*)d_in[19];
    const float* exit_w     = (const float*)d_in[20];
    const float* exit_b     = (const float*)d_in[21];
    const float* fnorm_w    = (const float*)d_in[22];
    const float* fnorm_b    = (const float*)d_in[23];
    const float* head_w     = (const float*)d_in[24];
    const float* head_b     = (const float*)d_in[25];
    float* out = (float*)d_out;

    float* ws = (float*)d_ws;
    float* H     = ws + 0;                  // 12608*192 fp32
    u16*   QKVB  = (u16*)(ws + 2420736);    // 12608*576 bf16
    u16*   XLNB  = (u16*)(ws + 6051840);    // 12608*192 bf16
    u16*   EXWT  = (u16*)(ws + 7262208);    // 3*1000*192 bf16
    u16*   HWT   = (u16*)(ws + 7550208);    // 1000*192 bf16
    u16*   POOLB = (u16*)(ws + 7646208);    // 64*192 bf16
    u16*   KVT   = (u16*)(ws + 19968000);   // 192*64*256 bf16
    u16*   MIDB  = (u16*)(ws + 21540864);   // im2col scratch (prologue only)
    u16*   ATNB  = (u16*)(ws + 26382336);   // 12608*192 bf16
    float* KSUM  = ws + 27617280;           // 192*256
    u16*   QKVWT = (u16*)(ws + 27666432);   // 12*576*192 bf16
    u16*   APWT  = (u16*)(ws + 28329984);   // 12*192*192 bf16
    u16*   F1WT  = (u16*)(ws + 28551168);   // 12*768*192 bf16
    u16*   F2WT  = (u16*)(ws + 29435904);   // 12*192*768 bf16
    u16*   PATWB = (u16*)(ws + 30320640);   // 192*768 bf16
    u16*   PMB   = (u16*)(ws + 30394368);   // 12*256*64 bf16
    u16*   P_IMB = MIDB;                    // im2col alias (prologue only)
    float* TOK   = (float*)QKVB;            // patch tokens alias (prologue only)

    if (ws_size < (size_t)30492672 * sizeof(float)) return;

    // ---- weight prep ----
    cvt_bf16<<<(147456 + 255) / 256, 256, 0, stream>>>(patch_w, PATWB, 147456);
    cvt_bf16<<<(196608 + 255) / 256, 256, 0, stream>>>(proj_mat, PMB, 196608);
    tr_bf16_t<<<dim3(18, 6, 12), 256, 0, stream>>>(qkv_w,   QKVWT, 192, 576);
    tr_bf16_t<<<dim3(6, 6, 12),  256, 0, stream>>>(attn_pw, APWT,  192, 192);
    tr_bf16_t<<<dim3(24, 6, 12), 256, 0, stream>>>(fc1_w,   F1WT,  192, 768);
    tr_bf16_t<<<dim3(6, 24, 12), 256, 0, stream>>>(fc2_w,   F2WT,  768, 192);
    tr_bf16_g<<<dim3(32, 6, 3), 256, 0, stream>>>(exit_w, EXWT, 192, 1000);
    tr_bf16_g<<<dim3(32, 6, 1), 256, 0, stream>>>(head_w, HWT,  192, 1000);

    // ---- patch embed ----
    im2col_kernel<<<(MPAT * 768 + 255) / 256, 256, 0, stream>>>(x, P_IMB, MPAT * 768);
    gemm_bf16<<<294, 256, 0, stream>>>(P_IMB, PATWB, patch_b,
                                       TOK, nullptr, MPAT, EMB, 768, 0, 3);
    embed_finish<<<(MTOT + 3) / 4, 256, 0, stream>>>(TOK, cls_token, pos_embed,
                                                     pe_norm_w, pe_norm_b,
                                                     norm1_w, norm1_b, H, XLNB);

    // ---- transformer layers ----
    for (int i = 0; i < 12; ++i) {
        const u16* qwt  = QKVWT + (size_t)i * 576 * 192;
        const u16* pwt  = APWT  + (size_t)i * 192 * 192;
        const u16* f1wt = F1WT  + (size_t)i * 768 * 192;
        const u16* f2wt = F2WT  + (size_t)i * 192 * 768;
        const u16* pmb  = PMB   + (size_t)i * 256 * 64;
        const float* qb  = qkv_b   + (size_t)i * 576;
        const float* pb  = attn_pb + (size_t)i * 192;
        const float* f1b = fc1_b   + (size_t)i * 768;

        gemm_bf16<<<891, 256, 0, stream>>>(XLNB, qwt, qb,
                                           nullptr, QKVB, MTOT, 576, 192, 3, 9);
        attn_pkv<<<dim3(4, BHT), 256, 0, stream>>>(QKVB, pmb, KVT, KSUM);
        attn_out<<<dim3(4, BHT), 256, 0, stream>>>(QKVB, pmb, KVT, KSUM, ATNB);
        gemm_ln<<<394, 256, 0, stream>>>(ATNB, pwt, pb,
                                         norm2_w + (size_t)i * EMB, norm2_b + (size_t)i * EMB,
                                         H, XLNB, EMB);
        const float* nw = (i < 11) ? norm1_w + (size_t)(i + 1) * EMB : nullptr;
        const float* nb = (i < 11) ? norm1_b + (size_t)(i + 1) * EMB : nullptr;
        mlp_ln<<<394, 256, 0, stream>>>(XLNB, f1wt, f1b, f2wt,
                                        fc2_b + (size_t)i * 192, nw, nb, H, XLNB);

        const int e = (i == 3) ? 0 : (i == 7) ? 1 : (i == 11) ? 2 : -1;
        if (e >= 0) {
            pool_kernel<<<BB, 384, 0, stream>>>(H, POOLB);
            gemm_cls<<<16, 256, 0, stream>>>(POOLB, EXWT + (size_t)e * 1000 * 192,
                                             exit_b + (size_t)e * 1000,
                                             out + (size_t)(1 + e) * BB * NCLS,
                                             NCLS, EMB);
        }
    }

    // ---- head ----
    ln192<<<(BB + 3) / 4, 256, 0, stream>>>(H, NTOK * EMB, fnorm_w, fnorm_b,
                                            XLNB, nullptr, BB);
    gemm_cls<<<16, 256, 0, stream>>>(XLNB, HWT, head_b, out, NCLS, EMB);
}